// Round 4
// baseline (612.747 us; speedup 1.0000x reference)
//
#include <hip/hip_runtime.h>
#include <math.h>

#define BDIM 2
#define TT 1024
#define NH 8
#define HD 64
#define NTOPK 16
#define NBH 16     // BDIM*NH
#define NTOK 16384 // NBH*TT

// ---------------------------------------------------------------------------
// Collapse the linear-linear pair MLPs into 128-dim fp64 vectors.
// wphid[r] = sum_c Wpi[r,c]*Wpo[c];  ccd[0] = bpi.Wpo + bpo
// wtaud[r] = sum_c Wti[r,c]*Wto[c];  ccd[1] = bti.Wto + bto
// (logit values are smooth in these — fp64 noise ~1e-13 is irrelevant)
// ---------------------------------------------------------------------------
__global__ __launch_bounds__(256) void k_collapse64(
    const float* __restrict__ Wpi, const float* __restrict__ bpi,
    const float* __restrict__ Wpo, const float* __restrict__ bpo,
    const float* __restrict__ Wti, const float* __restrict__ bti,
    const float* __restrict__ Wto, const float* __restrict__ bto,
    double* __restrict__ wphid, double* __restrict__ wtaud,
    double* __restrict__ ccd) {
  int tid = threadIdx.x;
  if (tid < 128) {
    double s = 0.;
    for (int c = 0; c < 512; ++c) s += (double)Wpi[tid * 512 + c] * (double)Wpo[c];
    wphid[tid] = s;
  } else {
    int r = tid - 128;
    double s = 0.;
    for (int c = 0; c < 256; ++c) s += (double)Wti[r * 256 + c] * (double)Wto[c];
    wtaud[r] = s;
  }
  int lane = tid & 63;
  if (tid < 64) {
    double p = 0.;
    for (int c = lane; c < 512; c += 64) p += (double)bpi[c] * (double)Wpo[c];
#pragma unroll
    for (int off = 32; off >= 1; off >>= 1) p += __shfl_xor(p, off, 64);
    if (lane == 0) ccd[0] = p + (double)bpo[0];
  } else if (tid < 128) {
    double p = 0.;
    for (int c = lane; c < 256; c += 64) p += (double)bti[c] * (double)Wto[c];
#pragma unroll
    for (int off = 32; off >= 1; off >>= 1) p += __shfl_xor(p, off, 64);
    if (lane == 0) ccd[1] = p + (double)bto[0];
  }
}

// ---------------------------------------------------------------------------
// fp32 GEMM with STRICT sequential-k fp32 FMA accumulation per output element
// (mimics BLAS/Eigen sgemm micro-kernel rounding: one fma per k, k=0..511 in
// order). out = A[2048,512] @ W[512,512] + bias.
// mode 0: row-major [2048,512];  mode 1: head-split [((b*8+h)*1024+t)*64+d].
// ---------------------------------------------------------------------------
__global__ __launch_bounds__(256) void k_gemm(
    const float* __restrict__ A, const float* __restrict__ W,
    const float* __restrict__ bias, float* __restrict__ out, int mode) {
  __shared__ float As[16][64];
  __shared__ float Bs[16][64];
  const int bm = blockIdx.y * 64;
  const int bn = blockIdx.x * 64;
  const int tid = threadIdx.x;
  const int tx = tid & 15;
  const int ty = tid >> 4;
  const int lr = tid >> 2;
  const int lc = (tid & 3) << 2;
  float acc[4][4] = {{0.f, 0.f, 0.f, 0.f}};
  for (int k0 = 0; k0 < 512; k0 += 16) {
    float4 av = *(const float4*)&A[(bm + lr) * 512 + k0 + lc];
    As[lc + 0][lr] = av.x;
    As[lc + 1][lr] = av.y;
    As[lc + 2][lr] = av.z;
    As[lc + 3][lr] = av.w;
    *(float4*)&Bs[ty][tx << 2] = *(const float4*)&W[(k0 + ty) * 512 + bn + (tx << 2)];
    __syncthreads();
#pragma unroll
    for (int kk = 0; kk < 16; ++kk) {
      float a0 = As[kk][ty * 4 + 0];
      float a1 = As[kk][ty * 4 + 1];
      float a2 = As[kk][ty * 4 + 2];
      float a3 = As[kk][ty * 4 + 3];
      float4 b = *(const float4*)&Bs[kk][tx << 2];
      acc[0][0] = fmaf(a0, b.x, acc[0][0]);
      acc[0][1] = fmaf(a0, b.y, acc[0][1]);
      acc[0][2] = fmaf(a0, b.z, acc[0][2]);
      acc[0][3] = fmaf(a0, b.w, acc[0][3]);
      acc[1][0] = fmaf(a1, b.x, acc[1][0]);
      acc[1][1] = fmaf(a1, b.y, acc[1][1]);
      acc[1][2] = fmaf(a1, b.z, acc[1][2]);
      acc[1][3] = fmaf(a1, b.w, acc[1][3]);
      acc[2][0] = fmaf(a2, b.x, acc[2][0]);
      acc[2][1] = fmaf(a2, b.y, acc[2][1]);
      acc[2][2] = fmaf(a2, b.z, acc[2][2]);
      acc[2][3] = fmaf(a2, b.w, acc[2][3]);
      acc[3][0] = fmaf(a3, b.x, acc[3][0]);
      acc[3][1] = fmaf(a3, b.y, acc[3][1]);
      acc[3][2] = fmaf(a3, b.z, acc[3][2]);
      acc[3][3] = fmaf(a3, b.w, acc[3][3]);
    }
    __syncthreads();
  }
#pragma unroll
  for (int i = 0; i < 4; ++i) {
    int row = bm + ty * 4 + i;
    float4 r;
    r.x = acc[i][0] + bias[bn + tx * 4 + 0];
    r.y = acc[i][1] + bias[bn + tx * 4 + 1];
    r.z = acc[i][2] + bias[bn + tx * 4 + 2];
    r.w = acc[i][3] + bias[bn + tx * 4 + 3];
    if (mode == 0) {
      *(float4*)&out[row * 512 + bn + tx * 4] = r;
    } else {
      int bb = row >> 10;
      int tt2 = row & 1023;
      int head = bn >> 6;
      *(float4*)&out[(((bb * NH + head) * TT + tt2) << 6) + tx * 4] = r;
    }
  }
}

// ---------------------------------------------------------------------------
// Per-token scalars in fp64 from the fp32 Q/K (values are smooth; precision
// here only needs to beat the 2.7e-2 threshold, which fp64 trivially does).
// ---------------------------------------------------------------------------
__global__ __launch_bounds__(256) void k_tokscal64(
    const float* __restrict__ Qg, const float* __restrict__ Kg,
    const double* __restrict__ wphid, const float* __restrict__ Wta,
    const float* __restrict__ Wtb, const double* __restrict__ wtaud,
    double4* __restrict__ sqd4, double4* __restrict__ skd4) {
  __shared__ double wp[128], wa[128], wb[128], wt[128];
  int tid = threadIdx.x;
  if (tid < 128) {
    wp[tid] = wphid[tid];
    wa[tid] = (double)Wta[tid];
    wb[tid] = (double)Wtb[tid];
    wt[tid] = wtaud[tid];
  }
  __syncthreads();
  int tok = blockIdx.x * 256 + tid;
  const float* qr = Qg + (size_t)tok * 64;
  const float* kr = Kg + (size_t)tok * 64;
  double sp = 0., sa = 0., sb = 0., st = 0.;
  double kp = 0., ka = 0., kb2 = 0., kt = 0.;
#pragma unroll
  for (int d = 0; d < 64; ++d) {
    double q = (double)qr[d];
    double k = (double)kr[d];
    sp += q * wp[d];
    sa += q * wa[d];
    sb += q * wb[d];
    st += q * wt[d];
    kp += k * wp[64 + d];
    ka += k * wa[64 + d];
    kb2 += k * wb[64 + d];
    kt += k * wt[64 + d];
  }
  sqd4[tok] = make_double4(sp, sa, sb, st);
  skd4[tok] = make_double4(kp, ka, kb2, kt);
}

// ---------------------------------------------------------------------------
// Attention: fp32 scores via STRICT sequential-d fp32 FMA (BLAS-mimicking),
// top-16 directly on those fp32 scores (value desc, index asc — lax.top_k
// semantics), then fp64 logits/softmax/attend.
// Block: 256 threads (4 waves), 8 queries. Grid (128, 16).
// ---------------------------------------------------------------------------
__global__ __launch_bounds__(256) void k_attn(
    const float* __restrict__ Qg, const float* __restrict__ Kg,
    const float* __restrict__ Vg, const double4* __restrict__ sqd4,
    const double4* __restrict__ skd4, const double* __restrict__ ccd,
    const float* __restrict__ btaP, const float* __restrict__ btbP,
    float* __restrict__ C) {
  __shared__ float qs[8][64];      // 2 KB
  __shared__ float ks[64][65];     // 16.6 KB (padded: odd stride kills bank dups)
  __shared__ float sc[8][1024];    // 32 KB
  const int bh = blockIdx.y;
  const int q0 = blockIdx.x * 8;
  const int tid = threadIdx.x;
  const int lane = tid & 63;
  const int wv = tid >> 6;
#pragma unroll
  for (int i = 0; i < 2; ++i) {
    int idx = i * 256 + tid;
    qs[idx >> 6][idx & 63] = Qg[(size_t)(bh * TT + q0 + (idx >> 6)) * 64 + (idx & 63)];
  }
  const int q = tid >> 5;       // 0..7
  const int kpair = tid & 31;   // 2 consecutive keys each
  for (int ch = 0; ch < 16; ++ch) {
    const int kb = ch * 64;
    __syncthreads();  // protect ks from previous chunk's readers (and qs, first time)
#pragma unroll
    for (int i = 0; i < 16; ++i) {
      int idx = i * 256 + tid;  // 0..4095
      ks[idx >> 6][idx & 63] = Kg[(size_t)(bh * TT + kb + (idx >> 6)) * 64 + (idx & 63)];
    }
    __syncthreads();
    const float* qrow = &qs[q][0];
    const float* k1 = &ks[kpair * 2][0];
    const float* k2 = &ks[kpair * 2 + 1][0];
    float s1 = 0.f, s2 = 0.f;
#pragma unroll
    for (int d = 0; d < 64; ++d) {
      float qv = qrow[d];
      s1 = fmaf(qv, k1[d], s1);   // sequential fp32 FMA over d — BLAS order
      s2 = fmaf(qv, k2[d], s2);
    }
    sc[q][kb + kpair * 2] = s1;
    sc[q][kb + kpair * 2 + 1] = s2;
  }
  __syncthreads();

  const double cphi = ccd[0];
  const double ctau = ccd[1];
  const double bta0 = (double)btaP[0];
  const double btb0 = (double)btbP[0];
  const int bb = bh >> 3;
  const int hh = bh & 7;
  const float* Vbh = Vg + (size_t)bh * (TT * 64);

#pragma unroll 1
  for (int qq = 0; qq < 2; ++qq) {
    const int ql = wv * 2 + qq;
    const int qa = q0 + ql;
    const float* rowp = &sc[ql][0];
    // top-16 on the fp32 scores: per-lane 16 candidates (key = jj*64+lane)
    float v[16];
#pragma unroll
    for (int jj = 0; jj < 16; ++jj) v[jj] = rowp[jj * 64 + lane];
    float gv[4];
    int gj[4];
#pragma unroll
    for (int g = 0; g < 4; ++g) {
      gv[g] = v[4 * g];
      gj[g] = 4 * g;
#pragma unroll
      for (int e = 1; e < 4; ++e) {
        if (v[4 * g + e] > gv[g]) { gv[g] = v[4 * g + e]; gj[g] = 4 * g + e; }
      }
    }
    int myk = 0;  // lane it (<16) holds the it-th largest key index
#pragma unroll 1
    for (int it = 0; it < NTOPK; ++it) {
      float bvv = gv[0];
      int bjj = gj[0];
#pragma unroll
      for (int g = 1; g < 4; ++g) {
        if (gv[g] > bvv) { bvv = gv[g]; bjj = gj[g]; }
      }
      int bj = bjj * 64 + lane;
#pragma unroll
      for (int off = 32; off >= 1; off >>= 1) {
        float ov = __shfl_xor(bvv, off, 64);
        int oj = __shfl_xor(bj, off, 64);
        if (ov > bvv || (ov == bvv && oj < bj)) { bvv = ov; bj = oj; }
      }
      if (lane == it) myk = bj;
      int owner = bj & 63;
      int slot = bj >> 6;
      if (lane == owner) {
#pragma unroll
        for (int jj = 0; jj < 16; ++jj)
          if (jj == slot) v[jj] = -INFINITY;
        int g2 = slot >> 2;
#pragma unroll
        for (int g = 0; g < 4; ++g) {
          if (g == g2) {
            float ngv = v[4 * g];
            int ngj = 4 * g;
#pragma unroll
            for (int e = 1; e < 4; ++e) {
              if (v[4 * g + e] > ngv) { ngv = v[4 * g + e]; ngj = 4 * g + e; }
            }
            gv[g] = ngv;
            gj[g] = ngj;
          }
        }
      }
    }
    // fp64 logits on lanes 0..15
    double4 sq = sqd4[bh * TT + qa];
    double logit = -INFINITY;
    if (lane < 16) {
      double4 sk = skd4[bh * TT + myk];
      double phi = 1.0 / (1.0 + exp(-(sq.x + sk.x + cphi)));
      double ta = sq.y + sk.y + bta0;
      double tb = sq.z + sk.z + btb0;
      double ti = 1.0 / (1.0 + exp(-(ta * 1.0 + tb)));  // T_SCALAR = 1
      double tl = sq.w + sk.w + ctau;
      double tau = fmax(tl, 0.0) + log1p(exp(-fabs(tl))) + 1e-6;  // softplus+eps
      logit = phi / tau * (1.0 - exp(-tau * ti));
    }
    // fp64 softmax over the 16 (xor offsets 8..1 stay within 16-lane groups)
    double m = logit;
#pragma unroll
    for (int off = 8; off >= 1; off >>= 1) {
      double om = __shfl_xor(m, off, 64);
      m = fmax(m, om);
    }
    double e = (lane < 16) ? exp(logit - m) : 0.0;
    double ssum = e;
#pragma unroll
    for (int off = 8; off >= 1; off >>= 1) ssum += __shfl_xor(ssum, off, 64);
    double w = e / ssum;
    // attend: lane = dim d; weights/indices broadcast from lanes 0..15
    double outv = 0.0;
#pragma unroll
    for (int k2 = 0; k2 < NTOPK; ++k2) {
      double wk = __shfl(w, k2, 64);
      int ik = __shfl(myk, k2, 64);
      outv += wk * (double)Vbh[(size_t)ik * 64 + lane];
    }
    C[(bb * TT + qa) * 512 + hh * 64 + lane] = (float)outv;
  }
}

// ---------------------------------------------------------------------------
extern "C" void kernel_launch(void* const* d_in, const int* in_sizes, int n_in,
                              void* d_out, int out_size, void* d_ws, size_t ws_size,
                              hipStream_t stream) {
  (void)in_sizes; (void)n_in; (void)out_size; (void)ws_size;
  const float* x   = (const float*)d_in[0];
  const float* Wq  = (const float*)d_in[1];
  const float* bq  = (const float*)d_in[2];
  const float* Wk  = (const float*)d_in[3];
  const float* bk  = (const float*)d_in[4];
  const float* Wv  = (const float*)d_in[5];
  const float* bv  = (const float*)d_in[6];
  const float* Wo  = (const float*)d_in[7];
  const float* bo  = (const float*)d_in[8];
  const float* Wpi = (const float*)d_in[9];
  const float* bpi = (const float*)d_in[10];
  const float* Wpo = (const float*)d_in[11];
  const float* bpo = (const float*)d_in[12];
  const float* Wta = (const float*)d_in[13];
  const float* bta = (const float*)d_in[14];
  const float* Wtb = (const float*)d_in[15];
  const float* btb = (const float*)d_in[16];
  const float* Wti = (const float*)d_in[17];
  const float* bti = (const float*)d_in[18];
  const float* Wto = (const float*)d_in[19];
  const float* bto = (const float*)d_in[20];

  double* wsd = (double*)d_ws;
  double4* sqd4 = (double4*)wsd;             // 65536 doubles
  double4* skd4 = (double4*)(wsd + 65536);   // 65536 doubles
  double* wphid = wsd + 131072;              // 128
  double* wtaud = wsd + 131200;              // 128
  double* ccd   = wsd + 131328;              // 2 (pad to 131332)
  float* fs = (float*)(wsd + 131332);
  float* Qf = fs;                  // [B,H,T,64] = 1,048,576 floats
  float* Kf = fs + 1048576;
  float* Vf = fs + 2097152;
  float* Cf = fs + 3145728;        // combined [B,T,512]

  hipLaunchKernelGGL(k_collapse64, dim3(1), dim3(256), 0, stream,
                     Wpi, bpi, Wpo, bpo, Wti, bti, Wto, bto, wphid, wtaud, ccd);
  dim3 gg(8, 32);
  hipLaunchKernelGGL(k_gemm, gg, dim3(256), 0, stream, x, Wq, bq, Qf, 1);
  hipLaunchKernelGGL(k_gemm, gg, dim3(256), 0, stream, x, Wk, bk, Kf, 1);
  hipLaunchKernelGGL(k_gemm, gg, dim3(256), 0, stream, x, Wv, bv, Vf, 1);
  hipLaunchKernelGGL(k_tokscal64, dim3(NTOK / 256), dim3(256), 0, stream,
                     Qf, Kf, wphid, Wta, Wtb, wtaud, sqd4, skd4);
  hipLaunchKernelGGL(k_attn, dim3(TT / 8, NBH), dim3(256), 0, stream,
                     Qf, Kf, Vf, sqd4, skd4, ccd, bta, btb, Cf);
  hipLaunchKernelGGL(k_gemm, gg, dim3(256), 0, stream, Cf, Wo, bo, (float*)d_out, 0);
}

// Round 5
// 572.838 us; speedup vs baseline: 1.0697x; 1.0697x over previous
//
#include <hip/hip_runtime.h>
#include <math.h>

#define BDIM 2
#define TT 1024
#define NH 8
#define HD 64
#define NTOPK 16
#define NBH 16     // BDIM*NH
#define NTOK 16384 // NBH*TT

// ---------------------------------------------------------------------------
// Collapse the linear-linear pair MLPs into 128-dim fp64 vectors.
// Blocks 0..15: 16 rows each (16 lanes/row). Block 16: the two bias scalars.
// ---------------------------------------------------------------------------
__global__ __launch_bounds__(256) void k_collapse64(
    const float* __restrict__ Wpi, const float* __restrict__ bpi,
    const float* __restrict__ Wpo, const float* __restrict__ bpo,
    const float* __restrict__ Wti, const float* __restrict__ bti,
    const float* __restrict__ Wto, const float* __restrict__ bto,
    double* __restrict__ wphid, double* __restrict__ wtaud,
    double* __restrict__ ccd) {
  int tid = threadIdx.x;
  int blk = blockIdx.x;
  if (blk < 16) {
    int r = blk * 16 + (tid >> 4);
    int l = tid & 15;
    double s = 0.;
    if (r < 128) {
      for (int i = 0; i < 32; ++i)
        s += (double)Wpi[r * 512 + l + 16 * i] * (double)Wpo[l + 16 * i];
    } else {
      int rr = r - 128;
      for (int i = 0; i < 16; ++i)
        s += (double)Wti[rr * 256 + l + 16 * i] * (double)Wto[l + 16 * i];
    }
#pragma unroll
    for (int off = 8; off >= 1; off >>= 1) s += __shfl_xor(s, off, 64);
    if (l == 0) {
      if (r < 128) wphid[r] = s;
      else wtaud[r - 128] = s;
    }
  } else {
    int lane = tid & 63;
    if (tid < 64) {
      double p = 0.;
      for (int c = lane; c < 512; c += 64) p += (double)bpi[c] * (double)Wpo[c];
#pragma unroll
      for (int off = 32; off >= 1; off >>= 1) p += __shfl_xor(p, off, 64);
      if (lane == 0) ccd[0] = p + (double)bpo[0];
    } else if (tid < 128) {
      double p = 0.;
      for (int c = lane; c < 256; c += 64) p += (double)bti[c] * (double)Wto[c];
#pragma unroll
      for (int off = 32; off >= 1; off >>= 1) p += __shfl_xor(p, off, 64);
      if (lane == 0) ccd[1] = p + (double)bto[0];
    }
  }
}

// ---------------------------------------------------------------------------
// fp32 GEMM, strict sequential-k fp32 FMA per output element (BLAS-order —
// this rounding pattern is what makes top-k selection match the reference).
// mode 0: row-major [2048,512];  mode 1: head-split [((b*8+h)*1024+t)*64+d].
// ---------------------------------------------------------------------------
__device__ __forceinline__ void gemm_body(
    const float* __restrict__ A, const float* __restrict__ W,
    const float* __restrict__ bias, float* __restrict__ out,
    int bm, int bn, int mode) {
  __shared__ float As[16][64];
  __shared__ float Bs[16][64];
  const int tid = threadIdx.x;
  const int tx = tid & 15;
  const int ty = tid >> 4;
  const int lr = tid >> 2;
  const int lc = (tid & 3) << 2;
  float acc[4][4] = {{0.f, 0.f, 0.f, 0.f}};
  for (int k0 = 0; k0 < 512; k0 += 16) {
    float4 av = *(const float4*)&A[(bm + lr) * 512 + k0 + lc];
    As[lc + 0][lr] = av.x;
    As[lc + 1][lr] = av.y;
    As[lc + 2][lr] = av.z;
    As[lc + 3][lr] = av.w;
    *(float4*)&Bs[ty][tx << 2] = *(const float4*)&W[(k0 + ty) * 512 + bn + (tx << 2)];
    __syncthreads();
#pragma unroll
    for (int kk = 0; kk < 16; ++kk) {
      float a0 = As[kk][ty * 4 + 0];
      float a1 = As[kk][ty * 4 + 1];
      float a2 = As[kk][ty * 4 + 2];
      float a3 = As[kk][ty * 4 + 3];
      float4 b = *(const float4*)&Bs[kk][tx << 2];
      acc[0][0] = fmaf(a0, b.x, acc[0][0]);
      acc[0][1] = fmaf(a0, b.y, acc[0][1]);
      acc[0][2] = fmaf(a0, b.z, acc[0][2]);
      acc[0][3] = fmaf(a0, b.w, acc[0][3]);
      acc[1][0] = fmaf(a1, b.x, acc[1][0]);
      acc[1][1] = fmaf(a1, b.y, acc[1][1]);
      acc[1][2] = fmaf(a1, b.z, acc[1][2]);
      acc[1][3] = fmaf(a1, b.w, acc[1][3]);
      acc[2][0] = fmaf(a2, b.x, acc[2][0]);
      acc[2][1] = fmaf(a2, b.y, acc[2][1]);
      acc[2][2] = fmaf(a2, b.z, acc[2][2]);
      acc[2][3] = fmaf(a2, b.w, acc[2][3]);
      acc[3][0] = fmaf(a3, b.x, acc[3][0]);
      acc[3][1] = fmaf(a3, b.y, acc[3][1]);
      acc[3][2] = fmaf(a3, b.z, acc[3][2]);
      acc[3][3] = fmaf(a3, b.w, acc[3][3]);
    }
    __syncthreads();
  }
#pragma unroll
  for (int i = 0; i < 4; ++i) {
    int row = bm + ty * 4 + i;
    float4 r;
    r.x = acc[i][0] + bias[bn + tx * 4 + 0];
    r.y = acc[i][1] + bias[bn + tx * 4 + 1];
    r.z = acc[i][2] + bias[bn + tx * 4 + 2];
    r.w = acc[i][3] + bias[bn + tx * 4 + 3];
    if (mode == 0) {
      *(float4*)&out[row * 512 + bn + tx * 4] = r;
    } else {
      int bb = row >> 10;
      int tt2 = row & 1023;
      int head = bn >> 6;
      *(float4*)&out[(((bb * NH + head) * TT + tt2) << 6) + tx * 4] = r;
    }
  }
}

__global__ __launch_bounds__(256) void k_gemm(
    const float* __restrict__ A, const float* __restrict__ W,
    const float* __restrict__ bias, float* __restrict__ out, int mode) {
  gemm_body(A, W, bias, out, blockIdx.y * 64, blockIdx.x * 64, mode);
}

// Fused QKV: grid.x = 24 (which = x>>3, bn = (x&7)*64), identical inner loop
// → bit-identical Q/K/V vs separate launches.
__global__ __launch_bounds__(256) void k_gemm_qkv(
    const float* __restrict__ A,
    const float* __restrict__ Wq, const float* __restrict__ bq,
    const float* __restrict__ Wk, const float* __restrict__ bk,
    const float* __restrict__ Wv, const float* __restrict__ bv,
    float* __restrict__ Qf, float* __restrict__ Kf, float* __restrict__ Vf) {
  int which = blockIdx.x >> 3;
  int bn = (blockIdx.x & 7) * 64;
  const float* W = (which == 0) ? Wq : (which == 1) ? Wk : Wv;
  const float* b = (which == 0) ? bq : (which == 1) ? bk : bv;
  float* out = (which == 0) ? Qf : (which == 1) ? Kf : Vf;
  gemm_body(A, W, b, out, blockIdx.y * 64, bn, 1);
}

// ---------------------------------------------------------------------------
// Per-token scalars in fp64 (smooth values — precision trivially sufficient).
// ---------------------------------------------------------------------------
__global__ __launch_bounds__(256) void k_tokscal64(
    const float* __restrict__ Qg, const float* __restrict__ Kg,
    const double* __restrict__ wphid, const float* __restrict__ Wta,
    const float* __restrict__ Wtb, const double* __restrict__ wtaud,
    double4* __restrict__ sqd4, double4* __restrict__ skd4) {
  __shared__ double wp[128], wa[128], wb[128], wt[128];
  int tid = threadIdx.x;
  if (tid < 128) {
    wp[tid] = wphid[tid];
    wa[tid] = (double)Wta[tid];
    wb[tid] = (double)Wtb[tid];
    wt[tid] = wtaud[tid];
  }
  __syncthreads();
  int tok = blockIdx.x * 256 + tid;
  const float* qr = Qg + (size_t)tok * 64;
  const float* kr = Kg + (size_t)tok * 64;
  double sp = 0., sa = 0., sb = 0., st = 0.;
  double kp = 0., ka = 0., kb2 = 0., kt = 0.;
#pragma unroll
  for (int d = 0; d < 64; ++d) {
    double q = (double)qr[d];
    double k = (double)kr[d];
    sp += q * wp[d];
    sa += q * wa[d];
    sb += q * wb[d];
    st += q * wt[d];
    kp += k * wp[64 + d];
    ka += k * wa[64 + d];
    kb2 += k * wb[64 + d];
    kt += k * wt[64 + d];
  }
  sqd4[tok] = make_double4(sp, sa, sb, st);
  skd4[tok] = make_double4(kp, ka, kb2, kt);
}

// ---------------------------------------------------------------------------
// Attention v2: lane = key. Each wave owns 4 disjoint 64-key chunks; K row
// loaded once from global into 16 float4 regs and reused across all 8
// queries (q via LDS b128 broadcast). Score = sequential fmaf over d — bit
// identical to the passing round-4 rounding. Then top-16 on fp32 scores
// (desc, index asc) + fp64 logits/softmax/attend.
// LDS: qs 2KB + sc 32KB = 34.3KB → 4 blocks/CU.
// ---------------------------------------------------------------------------
__global__ __launch_bounds__(256) void k_attn(
    const float* __restrict__ Qg, const float* __restrict__ Kg,
    const float* __restrict__ Vg, const double4* __restrict__ sqd4,
    const double4* __restrict__ skd4, const double* __restrict__ ccd,
    const float* __restrict__ btaP, const float* __restrict__ btbP,
    float* __restrict__ C) {
  __shared__ float qs[8][64];      // 2 KB
  __shared__ float sc[8][1024];    // 32 KB
  const int bh = blockIdx.y;
  const int q0 = blockIdx.x * 8;
  const int tid = threadIdx.x;
  const int lane = tid & 63;
  const int wv = tid >> 6;
  if (tid < 128) {
    int q = tid >> 4, d4 = (tid & 15) << 2;
    *(float4*)&qs[q][d4] = *(const float4*)&Qg[(size_t)(bh * TT + q0 + q) * 64 + d4];
  }
  __syncthreads();
  // ---- score phase ----
#pragma unroll 1
  for (int c = 0; c < 4; ++c) {
    const int kb = (c * 4 + wv) * 64;
    const float* krow = &Kg[(size_t)(bh * TT + kb + lane) * 64];
    float4 kr[16];
#pragma unroll
    for (int i = 0; i < 16; ++i) kr[i] = *(const float4*)&krow[i * 4];
#pragma unroll
    for (int q = 0; q < 8; ++q) {
      float s = 0.f;
#pragma unroll
      for (int i = 0; i < 16; ++i) {
        float4 q4 = *(const float4*)&qs[q][i * 4];  // broadcast read
        s = fmaf(q4.x, kr[i].x, s);
        s = fmaf(q4.y, kr[i].y, s);
        s = fmaf(q4.z, kr[i].z, s);
        s = fmaf(q4.w, kr[i].w, s);
      }
      sc[q][kb + lane] = s;
    }
  }
  __syncthreads();

  const double cphi = ccd[0];
  const double ctau = ccd[1];
  const double bta0 = (double)btaP[0];
  const double btb0 = (double)btbP[0];
  const int bb = bh >> 3;
  const int hh = bh & 7;
  const float* Vbh = Vg + (size_t)bh * (TT * 64);

#pragma unroll 1
  for (int qq = 0; qq < 2; ++qq) {
    const int ql = wv * 2 + qq;
    const int qa = q0 + ql;
    const float* rowp = &sc[ql][0];
    // top-16 on fp32 scores: per-lane 16 candidates (key = jj*64+lane)
    float v[16];
#pragma unroll
    for (int jj = 0; jj < 16; ++jj) v[jj] = rowp[jj * 64 + lane];
    float gv[4];
    int gj[4];
#pragma unroll
    for (int g = 0; g < 4; ++g) {
      gv[g] = v[4 * g];
      gj[g] = 4 * g;
#pragma unroll
      for (int e = 1; e < 4; ++e) {
        if (v[4 * g + e] > gv[g]) { gv[g] = v[4 * g + e]; gj[g] = 4 * g + e; }
      }
    }
    int myk = 0;  // lane it (<16) holds the it-th largest key index
#pragma unroll 1
    for (int it = 0; it < NTOPK; ++it) {
      float bvv = gv[0];
      int bjj = gj[0];
#pragma unroll
      for (int g = 1; g < 4; ++g) {
        if (gv[g] > bvv) { bvv = gv[g]; bjj = gj[g]; }
      }
      int bj = bjj * 64 + lane;
#pragma unroll
      for (int off = 32; off >= 1; off >>= 1) {
        float ov = __shfl_xor(bvv, off, 64);
        int oj = __shfl_xor(bj, off, 64);
        if (ov > bvv || (ov == bvv && oj < bj)) { bvv = ov; bj = oj; }
      }
      if (lane == it) myk = bj;
      int owner = bj & 63;
      int slot = bj >> 6;
      if (lane == owner) {
#pragma unroll
        for (int jj = 0; jj < 16; ++jj)
          if (jj == slot) v[jj] = -INFINITY;
        int g2 = slot >> 2;
#pragma unroll
        for (int g = 0; g < 4; ++g) {
          if (g == g2) {
            float ngv = v[4 * g];
            int ngj = 4 * g;
#pragma unroll
            for (int e = 1; e < 4; ++e) {
              if (v[4 * g + e] > ngv) { ngv = v[4 * g + e]; ngj = 4 * g + e; }
            }
            gv[g] = ngv;
            gj[g] = ngj;
          }
        }
      }
    }
    // fp64 logits on lanes 0..15
    double4 sq = sqd4[bh * TT + qa];
    double logit = -INFINITY;
    if (lane < 16) {
      double4 sk = skd4[bh * TT + myk];
      double phi = 1.0 / (1.0 + exp(-(sq.x + sk.x + cphi)));
      double ta = sq.y + sk.y + bta0;
      double tb = sq.z + sk.z + btb0;
      double ti = 1.0 / (1.0 + exp(-(ta * 1.0 + tb)));  // T_SCALAR = 1
      double tl = sq.w + sk.w + ctau;
      double tau = fmax(tl, 0.0) + log1p(exp(-fabs(tl))) + 1e-6;  // softplus+eps
      logit = phi / tau * (1.0 - exp(-tau * ti));
    }
    // fp64 softmax over the 16 (xor offsets 8..1 stay within 16-lane groups)
    double m = logit;
#pragma unroll
    for (int off = 8; off >= 1; off >>= 1) {
      double om = __shfl_xor(m, off, 64);
      m = fmax(m, om);
    }
    double e = (lane < 16) ? exp(logit - m) : 0.0;
    double ssum = e;
#pragma unroll
    for (int off = 8; off >= 1; off >>= 1) ssum += __shfl_xor(ssum, off, 64);
    double w = e / ssum;
    // attend: lane = dim d; weights/indices broadcast from lanes 0..15
    double outv = 0.0;
#pragma unroll
    for (int k2 = 0; k2 < NTOPK; ++k2) {
      double wk = __shfl(w, k2, 64);
      int ik = __shfl(myk, k2, 64);
      outv += wk * (double)Vbh[(size_t)ik * 64 + lane];
    }
    C[(bb * TT + qa) * 512 + hh * 64 + lane] = (float)outv;
  }
}

// ---------------------------------------------------------------------------
extern "C" void kernel_launch(void* const* d_in, const int* in_sizes, int n_in,
                              void* d_out, int out_size, void* d_ws, size_t ws_size,
                              hipStream_t stream) {
  (void)in_sizes; (void)n_in; (void)out_size; (void)ws_size;
  const float* x   = (const float*)d_in[0];
  const float* Wq  = (const float*)d_in[1];
  const float* bq  = (const float*)d_in[2];
  const float* Wk  = (const float*)d_in[3];
  const float* bk  = (const float*)d_in[4];
  const float* Wv  = (const float*)d_in[5];
  const float* bv  = (const float*)d_in[6];
  const float* Wo  = (const float*)d_in[7];
  const float* bo  = (const float*)d_in[8];
  const float* Wpi = (const float*)d_in[9];
  const float* bpi = (const float*)d_in[10];
  const float* Wpo = (const float*)d_in[11];
  const float* bpo = (const float*)d_in[12];
  const float* Wta = (const float*)d_in[13];
  const float* bta = (const float*)d_in[14];
  const float* Wtb = (const float*)d_in[15];
  const float* btb = (const float*)d_in[16];
  const float* Wti = (const float*)d_in[17];
  const float* bti = (const float*)d_in[18];
  const float* Wto = (const float*)d_in[19];
  const float* bto = (const float*)d_in[20];

  double* wsd = (double*)d_ws;
  double4* sqd4 = (double4*)wsd;             // 65536 doubles
  double4* skd4 = (double4*)(wsd + 65536);   // 65536 doubles
  double* wphid = wsd + 131072;              // 128
  double* wtaud = wsd + 131200;              // 128
  double* ccd   = wsd + 131328;              // 2 (pad to 131332)
  float* fs = (float*)(wsd + 131332);
  float* Qf = fs;                  // [B,H,T,64] = 1,048,576 floats
  float* Kf = fs + 1048576;
  float* Vf = fs + 2097152;
  float* Cf = fs + 3145728;        // combined [B,T,512]

  hipLaunchKernelGGL(k_collapse64, dim3(17), dim3(256), 0, stream,
                     Wpi, bpi, Wpo, bpo, Wti, bti, Wto, bto, wphid, wtaud, ccd);
  hipLaunchKernelGGL(k_gemm_qkv, dim3(24, 32), dim3(256), 0, stream,
                     x, Wq, bq, Wk, bk, Wv, bv, Qf, Kf, Vf);
  hipLaunchKernelGGL(k_tokscal64, dim3(NTOK / 256), dim3(256), 0, stream,
                     Qf, Kf, wphid, Wta, Wtb, wtaud, sqd4, skd4);
  hipLaunchKernelGGL(k_attn, dim3(TT / 8, NBH), dim3(256), 0, stream,
                     Qf, Kf, Vf, sqd4, skd4, ccd, bta, btb, Cf);
  hipLaunchKernelGGL(k_gemm, dim3(8, 32), dim3(256), 0, stream,
                     Cf, Wo, bo, (float*)d_out, 0);
}

// Round 6
// 300.970 us; speedup vs baseline: 2.0359x; 1.9033x over previous
//
#include <hip/hip_runtime.h>
#include <math.h>

#define BDIM 2
#define TT 1024
#define NH 8
#define HD 64
#define NTOPK 16
#define NBH 16     // BDIM*NH
#define NTOK 16384 // NBH*TT

// ---------------------------------------------------------------------------
// Collapse the linear-linear pair MLPs into 128-dim fp64 vectors.
// ---------------------------------------------------------------------------
__global__ __launch_bounds__(256) void k_collapse64(
    const float* __restrict__ Wpi, const float* __restrict__ bpi,
    const float* __restrict__ Wpo, const float* __restrict__ bpo,
    const float* __restrict__ Wti, const float* __restrict__ bti,
    const float* __restrict__ Wto, const float* __restrict__ bto,
    double* __restrict__ wphid, double* __restrict__ wtaud,
    double* __restrict__ ccd) {
  int tid = threadIdx.x;
  int blk = blockIdx.x;
  if (blk < 16) {
    int r = blk * 16 + (tid >> 4);
    int l = tid & 15;
    double s = 0.;
    if (r < 128) {
      for (int i = 0; i < 32; ++i)
        s += (double)Wpi[r * 512 + l + 16 * i] * (double)Wpo[l + 16 * i];
    } else {
      int rr = r - 128;
      for (int i = 0; i < 16; ++i)
        s += (double)Wti[rr * 256 + l + 16 * i] * (double)Wto[l + 16 * i];
    }
#pragma unroll
    for (int off = 8; off >= 1; off >>= 1) s += __shfl_xor(s, off, 64);
    if (l == 0) {
      if (r < 128) wphid[r] = s;
      else wtaud[r - 128] = s;
    }
  } else {
    int lane = tid & 63;
    if (tid < 64) {
      double p = 0.;
      for (int c = lane; c < 512; c += 64) p += (double)bpi[c] * (double)Wpo[c];
#pragma unroll
      for (int off = 32; off >= 1; off >>= 1) p += __shfl_xor(p, off, 64);
      if (lane == 0) ccd[0] = p + (double)bpo[0];
    } else if (tid < 128) {
      double p = 0.;
      for (int c = lane; c < 256; c += 64) p += (double)bti[c] * (double)Wto[c];
#pragma unroll
      for (int off = 32; off >= 1; off >>= 1) p += __shfl_xor(p, off, 64);
      if (lane == 0) ccd[1] = p + (double)bto[0];
    }
  }
}

// ---------------------------------------------------------------------------
// fp32 GEMM, strict sequential-k fp32 FMA per output element (BLAS-order —
// this rounding pattern makes top-k selection match the reference).
// ---------------------------------------------------------------------------
__device__ __forceinline__ void gemm_body(
    const float* __restrict__ A, const float* __restrict__ W,
    const float* __restrict__ bias, float* __restrict__ out,
    int bm, int bn, int mode) {
  __shared__ float As[16][64];
  __shared__ float Bs[16][64];
  const int tid = threadIdx.x;
  const int tx = tid & 15;
  const int ty = tid >> 4;
  const int lr = tid >> 2;
  const int lc = (tid & 3) << 2;
  float acc[4][4] = {{0.f, 0.f, 0.f, 0.f}};
  for (int k0 = 0; k0 < 512; k0 += 16) {
    float4 av = *(const float4*)&A[(bm + lr) * 512 + k0 + lc];
    As[lc + 0][lr] = av.x;
    As[lc + 1][lr] = av.y;
    As[lc + 2][lr] = av.z;
    As[lc + 3][lr] = av.w;
    *(float4*)&Bs[ty][tx << 2] = *(const float4*)&W[(k0 + ty) * 512 + bn + (tx << 2)];
    __syncthreads();
#pragma unroll
    for (int kk = 0; kk < 16; ++kk) {
      float a0 = As[kk][ty * 4 + 0];
      float a1 = As[kk][ty * 4 + 1];
      float a2 = As[kk][ty * 4 + 2];
      float a3 = As[kk][ty * 4 + 3];
      float4 b = *(const float4*)&Bs[kk][tx << 2];
      acc[0][0] = fmaf(a0, b.x, acc[0][0]);
      acc[0][1] = fmaf(a0, b.y, acc[0][1]);
      acc[0][2] = fmaf(a0, b.z, acc[0][2]);
      acc[0][3] = fmaf(a0, b.w, acc[0][3]);
      acc[1][0] = fmaf(a1, b.x, acc[1][0]);
      acc[1][1] = fmaf(a1, b.y, acc[1][1]);
      acc[1][2] = fmaf(a1, b.z, acc[1][2]);
      acc[1][3] = fmaf(a1, b.w, acc[1][3]);
      acc[2][0] = fmaf(a2, b.x, acc[2][0]);
      acc[2][1] = fmaf(a2, b.y, acc[2][1]);
      acc[2][2] = fmaf(a2, b.z, acc[2][2]);
      acc[2][3] = fmaf(a2, b.w, acc[2][3]);
      acc[3][0] = fmaf(a3, b.x, acc[3][0]);
      acc[3][1] = fmaf(a3, b.y, acc[3][1]);
      acc[3][2] = fmaf(a3, b.z, acc[3][2]);
      acc[3][3] = fmaf(a3, b.w, acc[3][3]);
    }
    __syncthreads();
  }
#pragma unroll
  for (int i = 0; i < 4; ++i) {
    int row = bm + ty * 4 + i;
    float4 r;
    r.x = acc[i][0] + bias[bn + tx * 4 + 0];
    r.y = acc[i][1] + bias[bn + tx * 4 + 1];
    r.z = acc[i][2] + bias[bn + tx * 4 + 2];
    r.w = acc[i][3] + bias[bn + tx * 4 + 3];
    if (mode == 0) {
      *(float4*)&out[row * 512 + bn + tx * 4] = r;
    } else {
      int bb = row >> 10;
      int tt2 = row & 1023;
      int head = bn >> 6;
      *(float4*)&out[(((bb * NH + head) * TT + tt2) << 6) + tx * 4] = r;
    }
  }
}

__global__ __launch_bounds__(256) void k_gemm(
    const float* __restrict__ A, const float* __restrict__ W,
    const float* __restrict__ bias, float* __restrict__ out, int mode) {
  gemm_body(A, W, bias, out, blockIdx.y * 64, blockIdx.x * 64, mode);
}

__global__ __launch_bounds__(256) void k_gemm_qkv(
    const float* __restrict__ A,
    const float* __restrict__ Wq, const float* __restrict__ bq,
    const float* __restrict__ Wk, const float* __restrict__ bk,
    const float* __restrict__ Wv, const float* __restrict__ bv,
    float* __restrict__ Qf, float* __restrict__ Kf, float* __restrict__ Vf) {
  int which = blockIdx.x >> 3;
  int bn = (blockIdx.x & 7) * 64;
  const float* W = (which == 0) ? Wq : (which == 1) ? Wk : Wv;
  const float* b = (which == 0) ? bq : (which == 1) ? bk : bv;
  float* out = (which == 0) ? Qf : (which == 1) ? Kf : Vf;
  gemm_body(A, W, b, out, blockIdx.y * 64, bn, 1);
}

// ---------------------------------------------------------------------------
// Per-token scalars in fp64.
// ---------------------------------------------------------------------------
__global__ __launch_bounds__(256) void k_tokscal64(
    const float* __restrict__ Qg, const float* __restrict__ Kg,
    const double* __restrict__ wphid, const float* __restrict__ Wta,
    const float* __restrict__ Wtb, const double* __restrict__ wtaud,
    double4* __restrict__ sqd4, double4* __restrict__ skd4) {
  __shared__ double wp[128], wa[128], wb[128], wt[128];
  int tid = threadIdx.x;
  if (tid < 128) {
    wp[tid] = wphid[tid];
    wa[tid] = (double)Wta[tid];
    wb[tid] = (double)Wtb[tid];
    wt[tid] = wtaud[tid];
  }
  __syncthreads();
  int tok = blockIdx.x * 256 + tid;
  const float* qr = Qg + (size_t)tok * 64;
  const float* kr = Kg + (size_t)tok * 64;
  double sp = 0., sa = 0., sb = 0., st = 0.;
  double kp = 0., ka = 0., kb2 = 0., kt = 0.;
#pragma unroll
  for (int d = 0; d < 64; ++d) {
    double q = (double)qr[d];
    double k = (double)kr[d];
    sp += q * wp[d];
    sa += q * wa[d];
    sb += q * wb[d];
    st += q * wt[d];
    kp += k * wp[64 + d];
    ka += k * wa[64 + d];
    kb2 += k * wb[64 + d];
    kt += k * wt[64 + d];
  }
  sqd4[tok] = make_double4(sp, sa, sb, st);
  skd4[tok] = make_double4(kp, ka, kb2, kt);
}

// ---------------------------------------------------------------------------
// K transpose per (b,h): Kf[bh][k][d] -> Kt[bh][d][k]. Bit-preserving copy.
// Grid (16 ktiles, 16 bh), 256 threads, 64x64 tile via padded LDS.
// ---------------------------------------------------------------------------
__global__ __launch_bounds__(256) void k_trans(
    const float* __restrict__ Kf, float* __restrict__ Kt) {
  __shared__ float tile[64][65];
  const int kt0 = blockIdx.x * 64;
  const int bh = blockIdx.y;
  const int t = threadIdx.x;
  const int rr = t >> 4;           // 0..15
  const int d4 = (t & 15) << 2;    // 0,4,..,60
#pragma unroll
  for (int i = 0; i < 4; ++i) {
    int row = i * 16 + rr;
    float4 v = *(const float4*)&Kf[((size_t)(bh * TT + kt0 + row)) * 64 + d4];
    tile[row][d4 + 0] = v.x;
    tile[row][d4 + 1] = v.y;
    tile[row][d4 + 2] = v.z;
    tile[row][d4 + 3] = v.w;
  }
  __syncthreads();
#pragma unroll
  for (int i = 0; i < 4; ++i) {
    int d = i * 16 + rr;
    int k4 = (t & 15) << 2;
    float4 v;
    v.x = tile[k4 + 0][d];
    v.y = tile[k4 + 1][d];
    v.z = tile[k4 + 2][d];
    v.w = tile[k4 + 3][d];
    *(float4*)&Kt[((size_t)(bh * 64 + d)) * 1024 + kt0 + k4] = v;
  }
}

// ---------------------------------------------------------------------------
// Score GEMM: Sc[bh][q][k] = sum_d Qf[bh][q][d] * Kt[bh][d][k].
// 128(q) x 64(k) block tile, 8x4 register tile, d=64 contraction as the
// serial inner loop with one fmaf per d per element — bit-identical rounding
// to the round-5 sequential-d chain.
// Grid (16 ktiles, 8 qtiles, 16 bh), 256 threads.
// ---------------------------------------------------------------------------
__global__ __launch_bounds__(256) void k_score(
    const float* __restrict__ Qf, const float* __restrict__ Kt,
    float* __restrict__ Sc) {
  __shared__ float As[16][132];   // [d-sub][q], padded
  __shared__ float Bs[16][64];    // [d-sub][k]
  const int bn = blockIdx.x * 64;
  const int bm = blockIdx.y * 128;
  const int bh = blockIdx.z;
  const float* A = Qf + (size_t)bh * (TT * 64);
  const float* W = Kt + (size_t)bh * (64 * 1024);
  float* out = Sc + (size_t)bh * (TT * 1024);
  const int tid = threadIdx.x;
  const int tx = tid & 15;        // k-group (4 k)
  const int ty = tid >> 4;        // q-group (8 q)
  const int lr = tid >> 2;        // 0..63 (staging row)
  const int lc = (tid & 3) << 2;  // 0,4,8,12 (staging d)
  float acc[8][4];
#pragma unroll
  for (int i = 0; i < 8; ++i)
#pragma unroll
    for (int j = 0; j < 4; ++j) acc[i][j] = 0.f;
  for (int k0 = 0; k0 < 64; k0 += 16) {
#pragma unroll
    for (int h = 0; h < 2; ++h) {
      int row = h * 64 + lr;
      float4 av = *(const float4*)&A[(size_t)(bm + row) * 64 + k0 + lc];
      As[lc + 0][row] = av.x;
      As[lc + 1][row] = av.y;
      As[lc + 2][row] = av.z;
      As[lc + 3][row] = av.w;
    }
    *(float4*)&Bs[ty][tx << 2] = *(const float4*)&W[(size_t)(k0 + ty) * 1024 + bn + (tx << 2)];
    __syncthreads();
#pragma unroll
    for (int kk = 0; kk < 16; ++kk) {
      float4 alo = *(const float4*)&As[kk][ty * 8];
      float4 ahi = *(const float4*)&As[kk][ty * 8 + 4];
      float4 b = *(const float4*)&Bs[kk][tx << 2];
      acc[0][0] = fmaf(alo.x, b.x, acc[0][0]);
      acc[0][1] = fmaf(alo.x, b.y, acc[0][1]);
      acc[0][2] = fmaf(alo.x, b.z, acc[0][2]);
      acc[0][3] = fmaf(alo.x, b.w, acc[0][3]);
      acc[1][0] = fmaf(alo.y, b.x, acc[1][0]);
      acc[1][1] = fmaf(alo.y, b.y, acc[1][1]);
      acc[1][2] = fmaf(alo.y, b.z, acc[1][2]);
      acc[1][3] = fmaf(alo.y, b.w, acc[1][3]);
      acc[2][0] = fmaf(alo.z, b.x, acc[2][0]);
      acc[2][1] = fmaf(alo.z, b.y, acc[2][1]);
      acc[2][2] = fmaf(alo.z, b.z, acc[2][2]);
      acc[2][3] = fmaf(alo.z, b.w, acc[2][3]);
      acc[3][0] = fmaf(alo.w, b.x, acc[3][0]);
      acc[3][1] = fmaf(alo.w, b.y, acc[3][1]);
      acc[3][2] = fmaf(alo.w, b.z, acc[3][2]);
      acc[3][3] = fmaf(alo.w, b.w, acc[3][3]);
      acc[4][0] = fmaf(ahi.x, b.x, acc[4][0]);
      acc[4][1] = fmaf(ahi.x, b.y, acc[4][1]);
      acc[4][2] = fmaf(ahi.x, b.z, acc[4][2]);
      acc[4][3] = fmaf(ahi.x, b.w, acc[4][3]);
      acc[5][0] = fmaf(ahi.y, b.x, acc[5][0]);
      acc[5][1] = fmaf(ahi.y, b.y, acc[5][1]);
      acc[5][2] = fmaf(ahi.y, b.z, acc[5][2]);
      acc[5][3] = fmaf(ahi.y, b.w, acc[5][3]);
      acc[6][0] = fmaf(ahi.z, b.x, acc[6][0]);
      acc[6][1] = fmaf(ahi.z, b.y, acc[6][1]);
      acc[6][2] = fmaf(ahi.z, b.z, acc[6][2]);
      acc[6][3] = fmaf(ahi.z, b.w, acc[6][3]);
      acc[7][0] = fmaf(ahi.w, b.x, acc[7][0]);
      acc[7][1] = fmaf(ahi.w, b.y, acc[7][1]);
      acc[7][2] = fmaf(ahi.w, b.z, acc[7][2]);
      acc[7][3] = fmaf(ahi.w, b.w, acc[7][3]);
    }
    __syncthreads();
  }
#pragma unroll
  for (int i = 0; i < 8; ++i) {
    float4 r = make_float4(acc[i][0], acc[i][1], acc[i][2], acc[i][3]);
    *(float4*)&out[(size_t)(bm + ty * 8 + i) * 1024 + bn + (tx << 2)] = r;
  }
}

// ---------------------------------------------------------------------------
// Top-16 + fp64 logits/softmax/attend. One WAVE per query; no LDS, no
// barriers; 4 waves/block, grid 4096. Same register algorithm as round 5
// (bit-identical selection and output).
// ---------------------------------------------------------------------------
__global__ __launch_bounds__(256) void k_topk(
    const float* __restrict__ Sc, const float* __restrict__ Vg,
    const double4* __restrict__ sqd4, const double4* __restrict__ skd4,
    const double* __restrict__ ccd, const float* __restrict__ btaP,
    const float* __restrict__ btbP, float* __restrict__ C) {
  const int tid = threadIdx.x;
  const int lane = tid & 63;
  const int wv = tid >> 6;
  const int qg = blockIdx.x * 4 + wv;   // 0..16383
  const int bh = qg >> 10;
  const int qa = qg & 1023;
  const int bb = bh >> 3;
  const int hh = bh & 7;
  const float* rowp = Sc + (size_t)qg * 1024;
  const float* Vbh = Vg + (size_t)bh * (TT * 64);

  float v[16];
#pragma unroll
  for (int jj = 0; jj < 16; ++jj) v[jj] = rowp[jj * 64 + lane];
  float gv[4];
  int gj[4];
#pragma unroll
  for (int g = 0; g < 4; ++g) {
    gv[g] = v[4 * g];
    gj[g] = 4 * g;
#pragma unroll
    for (int e = 1; e < 4; ++e) {
      if (v[4 * g + e] > gv[g]) { gv[g] = v[4 * g + e]; gj[g] = 4 * g + e; }
    }
  }
  int myk = 0;  // lane it (<16) holds the it-th largest key index
#pragma unroll 1
  for (int it = 0; it < NTOPK; ++it) {
    float bvv = gv[0];
    int bjj = gj[0];
#pragma unroll
    for (int g = 1; g < 4; ++g) {
      if (gv[g] > bvv) { bvv = gv[g]; bjj = gj[g]; }
    }
    int bj = bjj * 64 + lane;
#pragma unroll
    for (int off = 32; off >= 1; off >>= 1) {
      float ov = __shfl_xor(bvv, off, 64);
      int oj = __shfl_xor(bj, off, 64);
      if (ov > bvv || (ov == bvv && oj < bj)) { bvv = ov; bj = oj; }
    }
    if (lane == it) myk = bj;
    int owner = bj & 63;
    int slot = bj >> 6;
    if (lane == owner) {
#pragma unroll
      for (int jj = 0; jj < 16; ++jj)
        if (jj == slot) v[jj] = -INFINITY;
      int g2 = slot >> 2;
#pragma unroll
      for (int g = 0; g < 4; ++g) {
        if (g == g2) {
          float ngv = v[4 * g];
          int ngj = 4 * g;
#pragma unroll
          for (int e = 1; e < 4; ++e) {
            if (v[4 * g + e] > ngv) { ngv = v[4 * g + e]; ngj = 4 * g + e; }
          }
          gv[g] = ngv;
          gj[g] = ngj;
        }
      }
    }
  }
  const double cphi = ccd[0];
  const double ctau = ccd[1];
  const double bta0 = (double)btaP[0];
  const double btb0 = (double)btbP[0];
  double4 sq = sqd4[qg];
  double logit = -INFINITY;
  if (lane < 16) {
    double4 sk = skd4[bh * TT + myk];
    double phi = 1.0 / (1.0 + exp(-(sq.x + sk.x + cphi)));
    double ta = sq.y + sk.y + bta0;
    double tb = sq.z + sk.z + btb0;
    double ti = 1.0 / (1.0 + exp(-(ta * 1.0 + tb)));  // T_SCALAR = 1
    double tl = sq.w + sk.w + ctau;
    double tau = fmax(tl, 0.0) + log1p(exp(-fabs(tl))) + 1e-6;  // softplus+eps
    logit = phi / tau * (1.0 - exp(-tau * ti));
  }
  double m = logit;
#pragma unroll
  for (int off = 8; off >= 1; off >>= 1) {
    double om = __shfl_xor(m, off, 64);
    m = fmax(m, om);
  }
  double e = (lane < 16) ? exp(logit - m) : 0.0;
  double ssum = e;
#pragma unroll
  for (int off = 8; off >= 1; off >>= 1) ssum += __shfl_xor(ssum, off, 64);
  double w = e / ssum;
  double outv = 0.0;
#pragma unroll
  for (int k2 = 0; k2 < NTOPK; ++k2) {
    double wk = __shfl(w, k2, 64);
    int ik = __shfl(myk, k2, 64);
    outv += wk * (double)Vbh[(size_t)ik * 64 + lane];
  }
  C[(bb * TT + qa) * 512 + hh * 64 + lane] = (float)outv;
}

// ---------------------------------------------------------------------------
// Fallback fused attention (round-5 path) for small workspaces.
// ---------------------------------------------------------------------------
__global__ __launch_bounds__(256) void k_attn(
    const float* __restrict__ Qg, const float* __restrict__ Kg,
    const float* __restrict__ Vg, const double4* __restrict__ sqd4,
    const double4* __restrict__ skd4, const double* __restrict__ ccd,
    const float* __restrict__ btaP, const float* __restrict__ btbP,
    float* __restrict__ C) {
  __shared__ float qs[8][64];
  __shared__ float sc[8][1024];
  const int bh = blockIdx.y;
  const int q0 = blockIdx.x * 8;
  const int tid = threadIdx.x;
  const int lane = tid & 63;
  const int wv = tid >> 6;
  if (tid < 128) {
    int q = tid >> 4, d4 = (tid & 15) << 2;
    *(float4*)&qs[q][d4] = *(const float4*)&Qg[(size_t)(bh * TT + q0 + q) * 64 + d4];
  }
  __syncthreads();
#pragma unroll 1
  for (int c = 0; c < 4; ++c) {
    const int kb = (c * 4 + wv) * 64;
    const float* krow = &Kg[(size_t)(bh * TT + kb + lane) * 64];
    float4 kr[16];
#pragma unroll
    for (int i = 0; i < 16; ++i) kr[i] = *(const float4*)&krow[i * 4];
#pragma unroll
    for (int q = 0; q < 8; ++q) {
      float s = 0.f;
#pragma unroll
      for (int i = 0; i < 16; ++i) {
        float4 q4 = *(const float4*)&qs[q][i * 4];
        s = fmaf(q4.x, kr[i].x, s);
        s = fmaf(q4.y, kr[i].y, s);
        s = fmaf(q4.z, kr[i].z, s);
        s = fmaf(q4.w, kr[i].w, s);
      }
      sc[q][kb + lane] = s;
    }
  }
  __syncthreads();
  const double cphi = ccd[0];
  const double ctau = ccd[1];
  const double bta0 = (double)btaP[0];
  const double btb0 = (double)btbP[0];
  const int bb = bh >> 3;
  const int hh = bh & 7;
  const float* Vbh = Vg + (size_t)bh * (TT * 64);
#pragma unroll 1
  for (int qq = 0; qq < 2; ++qq) {
    const int ql = wv * 2 + qq;
    const int qa = q0 + ql;
    const float* rowp = &sc[ql][0];
    float v[16];
#pragma unroll
    for (int jj = 0; jj < 16; ++jj) v[jj] = rowp[jj * 64 + lane];
    float gv[4];
    int gj[4];
#pragma unroll
    for (int g = 0; g < 4; ++g) {
      gv[g] = v[4 * g];
      gj[g] = 4 * g;
#pragma unroll
      for (int e = 1; e < 4; ++e) {
        if (v[4 * g + e] > gv[g]) { gv[g] = v[4 * g + e]; gj[g] = 4 * g + e; }
      }
    }
    int myk = 0;
#pragma unroll 1
    for (int it = 0; it < NTOPK; ++it) {
      float bvv = gv[0];
      int bjj = gj[0];
#pragma unroll
      for (int g = 1; g < 4; ++g) {
        if (gv[g] > bvv) { bvv = gv[g]; bjj = gj[g]; }
      }
      int bj = bjj * 64 + lane;
#pragma unroll
      for (int off = 32; off >= 1; off >>= 1) {
        float ov = __shfl_xor(bvv, off, 64);
        int oj = __shfl_xor(bj, off, 64);
        if (ov > bvv || (ov == bvv && oj < bj)) { bvv = ov; bj = oj; }
      }
      if (lane == it) myk = bj;
      int owner = bj & 63;
      int slot = bj >> 6;
      if (lane == owner) {
#pragma unroll
        for (int jj = 0; jj < 16; ++jj)
          if (jj == slot) v[jj] = -INFINITY;
        int g2 = slot >> 2;
#pragma unroll
        for (int g = 0; g < 4; ++g) {
          if (g == g2) {
            float ngv = v[4 * g];
            int ngj = 4 * g;
#pragma unroll
            for (int e = 1; e < 4; ++e) {
              if (v[4 * g + e] > ngv) { ngv = v[4 * g + e]; ngj = 4 * g + e; }
            }
            gv[g] = ngv;
            gj[g] = ngj;
          }
        }
      }
    }
    double4 sq = sqd4[bh * TT + qa];
    double logit = -INFINITY;
    if (lane < 16) {
      double4 sk = skd4[bh * TT + myk];
      double phi = 1.0 / (1.0 + exp(-(sq.x + sk.x + cphi)));
      double ta = sq.y + sk.y + bta0;
      double tb = sq.z + sk.z + btb0;
      double ti = 1.0 / (1.0 + exp(-(ta * 1.0 + tb)));
      double tl = sq.w + sk.w + ctau;
      double tau = fmax(tl, 0.0) + log1p(exp(-fabs(tl))) + 1e-6;
      logit = phi / tau * (1.0 - exp(-tau * ti));
    }
    double m = logit;
#pragma unroll
    for (int off = 8; off >= 1; off >>= 1) {
      double om = __shfl_xor(m, off, 64);
      m = fmax(m, om);
    }
    double e = (lane < 16) ? exp(logit - m) : 0.0;
    double ssum = e;
#pragma unroll
    for (int off = 8; off >= 1; off >>= 1) ssum += __shfl_xor(ssum, off, 64);
    double w = e / ssum;
    double outv = 0.0;
#pragma unroll
    for (int k2 = 0; k2 < NTOPK; ++k2) {
      double wk = __shfl(w, k2, 64);
      int ik = __shfl(myk, k2, 64);
      outv += wk * (double)Vbh[(size_t)ik * 64 + lane];
    }
    C[(bb * TT + qa) * 512 + hh * 64 + lane] = (float)outv;
  }
}

// ---------------------------------------------------------------------------
extern "C" void kernel_launch(void* const* d_in, const int* in_sizes, int n_in,
                              void* d_out, int out_size, void* d_ws, size_t ws_size,
                              hipStream_t stream) {
  (void)in_sizes; (void)n_in; (void)out_size;
  const float* x   = (const float*)d_in[0];
  const float* Wq  = (const float*)d_in[1];
  const float* bq  = (const float*)d_in[2];
  const float* Wk  = (const float*)d_in[3];
  const float* bk  = (const float*)d_in[4];
  const float* Wv  = (const float*)d_in[5];
  const float* bv  = (const float*)d_in[6];
  const float* Wo  = (const float*)d_in[7];
  const float* bo  = (const float*)d_in[8];
  const float* Wpi = (const float*)d_in[9];
  const float* bpi = (const float*)d_in[10];
  const float* Wpo = (const float*)d_in[11];
  const float* bpo = (const float*)d_in[12];
  const float* Wta = (const float*)d_in[13];
  const float* bta = (const float*)d_in[14];
  const float* Wtb = (const float*)d_in[15];
  const float* btb = (const float*)d_in[16];
  const float* Wti = (const float*)d_in[17];
  const float* bti = (const float*)d_in[18];
  const float* Wto = (const float*)d_in[19];
  const float* bto = (const float*)d_in[20];

  double* wsd = (double*)d_ws;
  double4* sqd4 = (double4*)wsd;             // 65536 doubles
  double4* skd4 = (double4*)(wsd + 65536);   // 65536 doubles
  double* wphid = wsd + 131072;              // 128
  double* wtaud = wsd + 131200;              // 128
  double* ccd   = wsd + 131328;              // 2 (pad to 131332)
  float* fs = (float*)(wsd + 131332);
  float* Qf = fs;                  // 1,048,576 floats
  float* Kf = fs + 1048576;
  float* Vf = fs + 2097152;
  float* Cf = fs + 3145728;
  float* Kt = fs + 4194304;        // 1,048,576 floats (K^T per bh)
  float* Sc = fs + 5242880;        // 16,777,216 floats (scores, 64 MB)
  const size_t need = (size_t)131332 * 8 + (size_t)(5242880 + 16777216) * 4;

  hipLaunchKernelGGL(k_collapse64, dim3(17), dim3(256), 0, stream,
                     Wpi, bpi, Wpo, bpo, Wti, bti, Wto, bto, wphid, wtaud, ccd);
  hipLaunchKernelGGL(k_gemm_qkv, dim3(24, 32), dim3(256), 0, stream,
                     x, Wq, bq, Wk, bk, Wv, bv, Qf, Kf, Vf);
  hipLaunchKernelGGL(k_tokscal64, dim3(NTOK / 256), dim3(256), 0, stream,
                     Qf, Kf, wphid, Wta, Wtb, wtaud, sqd4, skd4);
  if (ws_size >= need) {
    hipLaunchKernelGGL(k_trans, dim3(16, 16), dim3(256), 0, stream, Kf, Kt);
    hipLaunchKernelGGL(k_score, dim3(16, 8, 16), dim3(256), 0, stream, Qf, Kt, Sc);
    hipLaunchKernelGGL(k_topk, dim3(NTOK / 4), dim3(256), 0, stream,
                       Sc, Vf, sqd4, skd4, ccd, bta, btb, Cf);
  } else {
    hipLaunchKernelGGL(k_attn, dim3(TT / 8, NBH), dim3(256), 0, stream,
                       Qf, Kf, Vf, sqd4, skd4, ccd, bta, btb, Cf);
  }
  hipLaunchKernelGGL(k_gemm, dim3(8, 32), dim3(256), 0, stream,
                     Cf, Wo, bo, (float*)d_out, 0);
}

// Round 7
// 275.983 us; speedup vs baseline: 2.2202x; 1.0905x over previous
//
#include <hip/hip_runtime.h>
#include <math.h>

#define BDIM 2
#define TT 1024
#define NH 8
#define HD 64
#define NTOPK 16
#define NBH 16     // BDIM*NH
#define NTOK 16384 // NBH*TT

// ---------------------------------------------------------------------------
// Collapse the linear-linear pair MLPs into 128-dim fp64 vectors.
// ---------------------------------------------------------------------------
__global__ __launch_bounds__(256) void k_collapse64(
    const float* __restrict__ Wpi, const float* __restrict__ bpi,
    const float* __restrict__ Wpo, const float* __restrict__ bpo,
    const float* __restrict__ Wti, const float* __restrict__ bti,
    const float* __restrict__ Wto, const float* __restrict__ bto,
    double* __restrict__ wphid, double* __restrict__ wtaud,
    double* __restrict__ ccd) {
  int tid = threadIdx.x;
  int blk = blockIdx.x;
  if (blk < 16) {
    int r = blk * 16 + (tid >> 4);
    int l = tid & 15;
    double s = 0.;
    if (r < 128) {
      for (int i = 0; i < 32; ++i)
        s += (double)Wpi[r * 512 + l + 16 * i] * (double)Wpo[l + 16 * i];
    } else {
      int rr = r - 128;
      for (int i = 0; i < 16; ++i)
        s += (double)Wti[rr * 256 + l + 16 * i] * (double)Wto[l + 16 * i];
    }
#pragma unroll
    for (int off = 8; off >= 1; off >>= 1) s += __shfl_xor(s, off, 64);
    if (l == 0) {
      if (r < 128) wphid[r] = s;
      else wtaud[r - 128] = s;
    }
  } else {
    int lane = tid & 63;
    if (tid < 64) {
      double p = 0.;
      for (int c = lane; c < 512; c += 64) p += (double)bpi[c] * (double)Wpo[c];
#pragma unroll
      for (int off = 32; off >= 1; off >>= 1) p += __shfl_xor(p, off, 64);
      if (lane == 0) ccd[0] = p + (double)bpo[0];
    } else if (tid < 128) {
      double p = 0.;
      for (int c = lane; c < 256; c += 64) p += (double)bti[c] * (double)Wto[c];
#pragma unroll
      for (int off = 32; off >= 1; off >>= 1) p += __shfl_xor(p, off, 64);
      if (lane == 0) ccd[1] = p + (double)bto[0];
    }
  }
}

// ---------------------------------------------------------------------------
// fp32 GEMM, strict sequential-k fp32 FMA per output element (BLAS-order —
// this rounding pattern makes top-k selection match the reference).
// A-fragment now read as one b128 (As[kk][ty*4..+3] contiguous) — same
// values, same fmaf order → bit-exact vs previous rounds.
// ---------------------------------------------------------------------------
__device__ __forceinline__ void gemm_body(
    const float* __restrict__ A, const float* __restrict__ W,
    const float* __restrict__ bias, float* __restrict__ out,
    int bm, int bn, int mode) {
  __shared__ float As[16][64];
  __shared__ float Bs[16][64];
  const int tid = threadIdx.x;
  const int tx = tid & 15;
  const int ty = tid >> 4;
  const int lr = tid >> 2;
  const int lc = (tid & 3) << 2;
  float acc[4][4] = {{0.f, 0.f, 0.f, 0.f}};
  for (int k0 = 0; k0 < 512; k0 += 16) {
    float4 av = *(const float4*)&A[(bm + lr) * 512 + k0 + lc];
    As[lc + 0][lr] = av.x;
    As[lc + 1][lr] = av.y;
    As[lc + 2][lr] = av.z;
    As[lc + 3][lr] = av.w;
    *(float4*)&Bs[ty][tx << 2] = *(const float4*)&W[(k0 + ty) * 512 + bn + (tx << 2)];
    __syncthreads();
#pragma unroll
    for (int kk = 0; kk < 16; ++kk) {
      float4 a = *(const float4*)&As[kk][ty * 4];
      float4 b = *(const float4*)&Bs[kk][tx << 2];
      acc[0][0] = fmaf(a.x, b.x, acc[0][0]);
      acc[0][1] = fmaf(a.x, b.y, acc[0][1]);
      acc[0][2] = fmaf(a.x, b.z, acc[0][2]);
      acc[0][3] = fmaf(a.x, b.w, acc[0][3]);
      acc[1][0] = fmaf(a.y, b.x, acc[1][0]);
      acc[1][1] = fmaf(a.y, b.y, acc[1][1]);
      acc[1][2] = fmaf(a.y, b.z, acc[1][2]);
      acc[1][3] = fmaf(a.y, b.w, acc[1][3]);
      acc[2][0] = fmaf(a.z, b.x, acc[2][0]);
      acc[2][1] = fmaf(a.z, b.y, acc[2][1]);
      acc[2][2] = fmaf(a.z, b.z, acc[2][2]);
      acc[2][3] = fmaf(a.z, b.w, acc[2][3]);
      acc[3][0] = fmaf(a.w, b.x, acc[3][0]);
      acc[3][1] = fmaf(a.w, b.y, acc[3][1]);
      acc[3][2] = fmaf(a.w, b.z, acc[3][2]);
      acc[3][3] = fmaf(a.w, b.w, acc[3][3]);
    }
    __syncthreads();
  }
#pragma unroll
  for (int i = 0; i < 4; ++i) {
    int row = bm + ty * 4 + i;
    float4 r;
    r.x = acc[i][0] + bias[bn + tx * 4 + 0];
    r.y = acc[i][1] + bias[bn + tx * 4 + 1];
    r.z = acc[i][2] + bias[bn + tx * 4 + 2];
    r.w = acc[i][3] + bias[bn + tx * 4 + 3];
    if (mode == 0) {
      *(float4*)&out[row * 512 + bn + tx * 4] = r;
    } else {
      int bb = row >> 10;
      int tt2 = row & 1023;
      int head = bn >> 6;
      *(float4*)&out[(((bb * NH + head) * TT + tt2) << 6) + tx * 4] = r;
    }
  }
}

__global__ __launch_bounds__(256) void k_gemm(
    const float* __restrict__ A, const float* __restrict__ W,
    const float* __restrict__ bias, float* __restrict__ out, int mode) {
  gemm_body(A, W, bias, out, blockIdx.y * 64, blockIdx.x * 64, mode);
}

__global__ __launch_bounds__(256) void k_gemm_qkv(
    const float* __restrict__ A,
    const float* __restrict__ Wq, const float* __restrict__ bq,
    const float* __restrict__ Wk, const float* __restrict__ bk,
    const float* __restrict__ Wv, const float* __restrict__ bv,
    float* __restrict__ Qf, float* __restrict__ Kf, float* __restrict__ Vf) {
  int which = blockIdx.x >> 3;
  int bn = (blockIdx.x & 7) * 64;
  const float* W = (which == 0) ? Wq : (which == 1) ? Wk : Wv;
  const float* b = (which == 0) ? bq : (which == 1) ? bk : bv;
  float* out = (which == 0) ? Qf : (which == 1) ? Kf : Vf;
  gemm_body(A, W, b, out, blockIdx.y * 64, bn, 1);
}

// ---------------------------------------------------------------------------
// Per-token scalars in fp64.
// ---------------------------------------------------------------------------
__global__ __launch_bounds__(256) void k_tokscal64(
    const float* __restrict__ Qg, const float* __restrict__ Kg,
    const double* __restrict__ wphid, const float* __restrict__ Wta,
    const float* __restrict__ Wtb, const double* __restrict__ wtaud,
    double4* __restrict__ sqd4, double4* __restrict__ skd4) {
  __shared__ double wp[128], wa[128], wb[128], wt[128];
  int tid = threadIdx.x;
  if (tid < 128) {
    wp[tid] = wphid[tid];
    wa[tid] = (double)Wta[tid];
    wb[tid] = (double)Wtb[tid];
    wt[tid] = wtaud[tid];
  }
  __syncthreads();
  int tok = blockIdx.x * 256 + tid;
  const float* qr = Qg + (size_t)tok * 64;
  const float* kr = Kg + (size_t)tok * 64;
  double sp = 0., sa = 0., sb = 0., st = 0.;
  double kp = 0., ka = 0., kb2 = 0., kt = 0.;
#pragma unroll
  for (int d = 0; d < 64; ++d) {
    double q = (double)qr[d];
    double k = (double)kr[d];
    sp += q * wp[d];
    sa += q * wa[d];
    sb += q * wb[d];
    st += q * wt[d];
    kp += k * wp[64 + d];
    ka += k * wa[64 + d];
    kb2 += k * wb[64 + d];
    kt += k * wt[64 + d];
  }
  sqd4[tok] = make_double4(sp, sa, sb, st);
  skd4[tok] = make_double4(kp, ka, kb2, kt);
}

// ---------------------------------------------------------------------------
// K transpose per (b,h): Kf[bh][k][d] -> Kt[bh][d][k]. Bit-preserving copy.
// ---------------------------------------------------------------------------
__global__ __launch_bounds__(256) void k_trans(
    const float* __restrict__ Kf, float* __restrict__ Kt) {
  __shared__ float tile[64][65];
  const int kt0 = blockIdx.x * 64;
  const int bh = blockIdx.y;
  const int t = threadIdx.x;
  const int rr = t >> 4;
  const int d4 = (t & 15) << 2;
#pragma unroll
  for (int i = 0; i < 4; ++i) {
    int row = i * 16 + rr;
    float4 v = *(const float4*)&Kf[((size_t)(bh * TT + kt0 + row)) * 64 + d4];
    tile[row][d4 + 0] = v.x;
    tile[row][d4 + 1] = v.y;
    tile[row][d4 + 2] = v.z;
    tile[row][d4 + 3] = v.w;
  }
  __syncthreads();
#pragma unroll
  for (int i = 0; i < 4; ++i) {
    int d = i * 16 + rr;
    int k4 = (t & 15) << 2;
    float4 v;
    v.x = tile[k4 + 0][d];
    v.y = tile[k4 + 1][d];
    v.z = tile[k4 + 2][d];
    v.w = tile[k4 + 3][d];
    *(float4*)&Kt[((size_t)(bh * 64 + d)) * 1024 + kt0 + k4] = v;
  }
}

// ---------------------------------------------------------------------------
// Score GEMM: Sc[bh][q][k] = sum_d Qf[bh][q][d] * Kt[bh][d][k].
// 128(q) x 64(k) tile, 8x4 register tile, BK=32 (half the barriers of r6).
// d ascending with one fmaf per d per element — bit-identical rounding.
// ---------------------------------------------------------------------------
__global__ __launch_bounds__(256) void k_score(
    const float* __restrict__ Qf, const float* __restrict__ Kt,
    float* __restrict__ Sc) {
  __shared__ float As[32][132];   // [d-sub][q], padded
  __shared__ float Bs[32][64];    // [d-sub][k]
  const int bn = blockIdx.x * 64;
  const int bm = blockIdx.y * 128;
  const int bh = blockIdx.z;
  const float* A = Qf + (size_t)bh * (TT * 64);
  const float* W = Kt + (size_t)bh * (64 * 1024);
  float* out = Sc + (size_t)bh * (TT * 1024);
  const int tid = threadIdx.x;
  const int tx = tid & 15;
  const int ty = tid >> 4;
  float acc[8][4];
#pragma unroll
  for (int i = 0; i < 8; ++i)
#pragma unroll
    for (int j = 0; j < 4; ++j) acc[i][j] = 0.f;
  for (int k0 = 0; k0 < 64; k0 += 32) {
#pragma unroll
    for (int i = 0; i < 4; ++i) {
      int idx = i * 256 + tid;      // 0..1023
      int row = idx >> 3;           // 0..127
      int c4 = (idx & 7) << 2;      // 0..28
      float4 av = *(const float4*)&A[(size_t)(bm + row) * 64 + k0 + c4];
      As[c4 + 0][row] = av.x;
      As[c4 + 1][row] = av.y;
      As[c4 + 2][row] = av.z;
      As[c4 + 3][row] = av.w;
    }
#pragma unroll
    for (int i = 0; i < 2; ++i) {
      int idx = i * 256 + tid;      // 0..511
      int br = idx >> 4;            // 0..31
      int bc = (idx & 15) << 2;
      *(float4*)&Bs[br][bc] = *(const float4*)&W[(size_t)(k0 + br) * 1024 + bn + bc];
    }
    __syncthreads();
#pragma unroll
    for (int kk = 0; kk < 32; ++kk) {
      float4 alo = *(const float4*)&As[kk][ty * 8];
      float4 ahi = *(const float4*)&As[kk][ty * 8 + 4];
      float4 b = *(const float4*)&Bs[kk][tx << 2];
      acc[0][0] = fmaf(alo.x, b.x, acc[0][0]);
      acc[0][1] = fmaf(alo.x, b.y, acc[0][1]);
      acc[0][2] = fmaf(alo.x, b.z, acc[0][2]);
      acc[0][3] = fmaf(alo.x, b.w, acc[0][3]);
      acc[1][0] = fmaf(alo.y, b.x, acc[1][0]);
      acc[1][1] = fmaf(alo.y, b.y, acc[1][1]);
      acc[1][2] = fmaf(alo.y, b.z, acc[1][2]);
      acc[1][3] = fmaf(alo.y, b.w, acc[1][3]);
      acc[2][0] = fmaf(alo.z, b.x, acc[2][0]);
      acc[2][1] = fmaf(alo.z, b.y, acc[2][1]);
      acc[2][2] = fmaf(alo.z, b.z, acc[2][2]);
      acc[2][3] = fmaf(alo.z, b.w, acc[2][3]);
      acc[3][0] = fmaf(alo.w, b.x, acc[3][0]);
      acc[3][1] = fmaf(alo.w, b.y, acc[3][1]);
      acc[3][2] = fmaf(alo.w, b.z, acc[3][2]);
      acc[3][3] = fmaf(alo.w, b.w, acc[3][3]);
      acc[4][0] = fmaf(ahi.x, b.x, acc[4][0]);
      acc[4][1] = fmaf(ahi.x, b.y, acc[4][1]);
      acc[4][2] = fmaf(ahi.x, b.z, acc[4][2]);
      acc[4][3] = fmaf(ahi.x, b.w, acc[4][3]);
      acc[5][0] = fmaf(ahi.y, b.x, acc[5][0]);
      acc[5][1] = fmaf(ahi.y, b.y, acc[5][1]);
      acc[5][2] = fmaf(ahi.y, b.z, acc[5][2]);
      acc[5][3] = fmaf(ahi.y, b.w, acc[5][3]);
      acc[6][0] = fmaf(ahi.z, b.x, acc[6][0]);
      acc[6][1] = fmaf(ahi.z, b.y, acc[6][1]);
      acc[6][2] = fmaf(ahi.z, b.z, acc[6][2]);
      acc[6][3] = fmaf(ahi.z, b.w, acc[6][3]);
      acc[7][0] = fmaf(ahi.w, b.x, acc[7][0]);
      acc[7][1] = fmaf(ahi.w, b.y, acc[7][1]);
      acc[7][2] = fmaf(ahi.w, b.z, acc[7][2]);
      acc[7][3] = fmaf(ahi.w, b.w, acc[7][3]);
    }
    __syncthreads();
  }
#pragma unroll
  for (int i = 0; i < 8; ++i) {
    float4 r = make_float4(acc[i][0], acc[i][1], acc[i][2], acc[i][3]);
    *(float4*)&out[(size_t)(bm + ty * 8 + i) * 1024 + bn + (tx << 2)] = r;
  }
}

// ---------------------------------------------------------------------------
// Top-16 + fp32 logits/softmax/attend. One WAVE per query. Selection is
// bit-exact (same scores, tie-break on global index); smooth path switched
// fp64 -> fp32 (error ~1e-5 << 2.7e-2 threshold, under the bf16 floor).
// Candidate s of lane maps to key index (s>>2)*256 + lane*4 + (s&3)
// (float4 loads); mapping is monotone in s per lane, so within-lane strict->
// selection still prefers the smaller global index on ties.
// ---------------------------------------------------------------------------
__global__ __launch_bounds__(256) void k_topk(
    const float* __restrict__ Sc, const float* __restrict__ Vg,
    const double4* __restrict__ sqd4, const double4* __restrict__ skd4,
    const double* __restrict__ ccd, const float* __restrict__ btaP,
    const float* __restrict__ btbP, float* __restrict__ C) {
  const int tid = threadIdx.x;
  const int lane = tid & 63;
  const int wv = tid >> 6;
  const int qg = blockIdx.x * 4 + wv;   // 0..16383
  const int bh = qg >> 10;
  const int qa = qg & 1023;
  const int bb = bh >> 3;
  const int hh = bh & 7;
  const float* rowp = Sc + (size_t)qg * 1024;
  const float* Vbh = Vg + (size_t)bh * (TT * 64);

  float v[16];
#pragma unroll
  for (int j4 = 0; j4 < 4; ++j4) {
    float4 t = *(const float4*)&rowp[j4 * 256 + lane * 4];
    v[j4 * 4 + 0] = t.x;
    v[j4 * 4 + 1] = t.y;
    v[j4 * 4 + 2] = t.z;
    v[j4 * 4 + 3] = t.w;
  }
  float gv[4];
  int gj[4];
#pragma unroll
  for (int g = 0; g < 4; ++g) {
    gv[g] = v[4 * g];
    gj[g] = 4 * g;
#pragma unroll
    for (int e = 1; e < 4; ++e) {
      if (v[4 * g + e] > gv[g]) { gv[g] = v[4 * g + e]; gj[g] = 4 * g + e; }
    }
  }
  int myk = 0;  // lane it (<16) holds the it-th largest key index
#pragma unroll 1
  for (int it = 0; it < NTOPK; ++it) {
    float bvv = gv[0];
    int bjj = gj[0];
#pragma unroll
    for (int g = 1; g < 4; ++g) {
      if (gv[g] > bvv) { bvv = gv[g]; bjj = gj[g]; }
    }
    // slot -> global key index
    int bj = ((bjj >> 2) << 8) + (lane << 2) + (bjj & 3);
#pragma unroll
    for (int off = 32; off >= 1; off >>= 1) {
      float ov = __shfl_xor(bvv, off, 64);
      int oj = __shfl_xor(bj, off, 64);
      if (ov > bvv || (ov == bvv && oj < bj)) { bvv = ov; bj = oj; }
    }
    if (lane == it) myk = bj;
    int owner = (bj >> 2) & 63;
    int slot = (((bj >> 8) << 2)) | (bj & 3);
    if (lane == owner) {
#pragma unroll
      for (int jj = 0; jj < 16; ++jj)
        if (jj == slot) v[jj] = -INFINITY;
      int g2 = slot >> 2;
#pragma unroll
      for (int g = 0; g < 4; ++g) {
        if (g == g2) {
          float ngv = v[4 * g];
          int ngj = 4 * g;
#pragma unroll
          for (int e = 1; e < 4; ++e) {
            if (v[4 * g + e] > ngv) { ngv = v[4 * g + e]; ngj = 4 * g + e; }
          }
          gv[g] = ngv;
          gj[g] = ngj;
        }
      }
    }
  }
  // fp32 logits on lanes 0..15 (additions of the fp64 token scalars done in
  // double, then rounded once — smooth path, ~1e-7 relative)
  const double cphi = ccd[0];
  const double ctau = ccd[1];
  const double bta0 = (double)btaP[0];
  const double btb0 = (double)btbP[0];
  double4 sq = sqd4[qg];
  float logit = -INFINITY;
  if (lane < 16) {
    double4 sk = skd4[bh * TT + myk];
    float xs = (float)(sq.x + sk.x + cphi);
    float ta = (float)(sq.y + sk.y + bta0);
    float tb = (float)(sq.z + sk.z + btb0);
    float tl = (float)(sq.w + sk.w + ctau);
    float phi = 1.f / (1.f + __expf(-xs));
    float ti = 1.f / (1.f + __expf(-(ta + tb)));          // T_SCALAR = 1
    float tau = fmaxf(tl, 0.f) + log1pf(__expf(-fabsf(tl))) + 1e-6f;
    logit = phi / tau * (1.f - __expf(-tau * ti));
  }
  float m = logit;
#pragma unroll
  for (int off = 8; off >= 1; off >>= 1) m = fmaxf(m, __shfl_xor(m, off, 64));
  float e = (lane < 16) ? __expf(logit - m) : 0.f;
  float ssum = e;
#pragma unroll
  for (int off = 8; off >= 1; off >>= 1) ssum += __shfl_xor(ssum, off, 64);
  float w = e / ssum;
  float outv = 0.f;
#pragma unroll
  for (int k2 = 0; k2 < NTOPK; ++k2) {
    float wk = __shfl(w, k2, 64);
    int ik = __shfl(myk, k2, 64);
    outv = fmaf(wk, Vbh[(size_t)ik * 64 + lane], outv);
  }
  C[(bb * TT + qa) * 512 + hh * 64 + lane] = outv;
}

// ---------------------------------------------------------------------------
// Fallback fused attention (round-5 path) for small workspaces.
// ---------------------------------------------------------------------------
__global__ __launch_bounds__(256) void k_attn(
    const float* __restrict__ Qg, const float* __restrict__ Kg,
    const float* __restrict__ Vg, const double4* __restrict__ sqd4,
    const double4* __restrict__ skd4, const double* __restrict__ ccd,
    const float* __restrict__ btaP, const float* __restrict__ btbP,
    float* __restrict__ C) {
  __shared__ float qs[8][64];
  __shared__ float sc[8][1024];
  const int bh = blockIdx.y;
  const int q0 = blockIdx.x * 8;
  const int tid = threadIdx.x;
  const int lane = tid & 63;
  const int wv = tid >> 6;
  if (tid < 128) {
    int q = tid >> 4, d4 = (tid & 15) << 2;
    *(float4*)&qs[q][d4] = *(const float4*)&Qg[(size_t)(bh * TT + q0 + q) * 64 + d4];
  }
  __syncthreads();
#pragma unroll 1
  for (int c = 0; c < 4; ++c) {
    const int kb = (c * 4 + wv) * 64;
    const float* krow = &Kg[(size_t)(bh * TT + kb + lane) * 64];
    float4 kr[16];
#pragma unroll
    for (int i = 0; i < 16; ++i) kr[i] = *(const float4*)&krow[i * 4];
#pragma unroll
    for (int q = 0; q < 8; ++q) {
      float s = 0.f;
#pragma unroll
      for (int i = 0; i < 16; ++i) {
        float4 q4 = *(const float4*)&qs[q][i * 4];
        s = fmaf(q4.x, kr[i].x, s);
        s = fmaf(q4.y, kr[i].y, s);
        s = fmaf(q4.z, kr[i].z, s);
        s = fmaf(q4.w, kr[i].w, s);
      }
      sc[q][kb + lane] = s;
    }
  }
  __syncthreads();
  const double cphi = ccd[0];
  const double ctau = ccd[1];
  const double bta0 = (double)btaP[0];
  const double btb0 = (double)btbP[0];
  const int bb = bh >> 3;
  const int hh = bh & 7;
  const float* Vbh = Vg + (size_t)bh * (TT * 64);
#pragma unroll 1
  for (int qq = 0; qq < 2; ++qq) {
    const int ql = wv * 2 + qq;
    const int qa = q0 + ql;
    const float* rowp = &sc[ql][0];
    float v[16];
#pragma unroll
    for (int jj = 0; jj < 16; ++jj) v[jj] = rowp[jj * 64 + lane];
    float gv[4];
    int gj[4];
#pragma unroll
    for (int g = 0; g < 4; ++g) {
      gv[g] = v[4 * g];
      gj[g] = 4 * g;
#pragma unroll
      for (int e = 1; e < 4; ++e) {
        if (v[4 * g + e] > gv[g]) { gv[g] = v[4 * g + e]; gj[g] = 4 * g + e; }
      }
    }
    int myk = 0;
#pragma unroll 1
    for (int it = 0; it < NTOPK; ++it) {
      float bvv = gv[0];
      int bjj = gj[0];
#pragma unroll
      for (int g = 1; g < 4; ++g) {
        if (gv[g] > bvv) { bvv = gv[g]; bjj = gj[g]; }
      }
      int bj = bjj * 64 + lane;
#pragma unroll
      for (int off = 32; off >= 1; off >>= 1) {
        float ov = __shfl_xor(bvv, off, 64);
        int oj = __shfl_xor(bj, off, 64);
        if (ov > bvv || (ov == bvv && oj < bj)) { bvv = ov; bj = oj; }
      }
      if (lane == it) myk = bj;
      int owner = bj & 63;
      int slot = bj >> 6;
      if (lane == owner) {
#pragma unroll
        for (int jj = 0; jj < 16; ++jj)
          if (jj == slot) v[jj] = -INFINITY;
        int g2 = slot >> 2;
#pragma unroll
        for (int g = 0; g < 4; ++g) {
          if (g == g2) {
            float ngv = v[4 * g];
            int ngj = 4 * g;
#pragma unroll
            for (int e = 1; e < 4; ++e) {
              if (v[4 * g + e] > ngv) { ngv = v[4 * g + e]; ngj = 4 * g + e; }
            }
            gv[g] = ngv;
            gj[g] = ngj;
          }
        }
      }
    }
    double4 sq = sqd4[bh * TT + qa];
    double logit = -INFINITY;
    if (lane < 16) {
      double4 sk = skd4[bh * TT + myk];
      double phi = 1.0 / (1.0 + exp(-(sq.x + sk.x + cphi)));
      double ta = sq.y + sk.y + bta0;
      double tb = sq.z + sk.z + btb0;
      double ti = 1.0 / (1.0 + exp(-(ta * 1.0 + tb)));
      double tl = sq.w + sk.w + ctau;
      double tau = fmax(tl, 0.0) + log1p(exp(-fabs(tl))) + 1e-6;
      logit = phi / tau * (1.0 - exp(-tau * ti));
    }
    double m = logit;
#pragma unroll
    for (int off = 8; off >= 1; off >>= 1) {
      double om = __shfl_xor(m, off, 64);
      m = fmax(m, om);
    }
    double e = (lane < 16) ? exp(logit - m) : 0.0;
    double ssum = e;
#pragma unroll
    for (int off = 8; off >= 1; off >>= 1) ssum += __shfl_xor(ssum, off, 64);
    double w = e / ssum;
    double outv = 0.0;
#pragma unroll
    for (int k2 = 0; k2 < NTOPK; ++k2) {
      double wk = __shfl(w, k2, 64);
      int ik = __shfl(myk, k2, 64);
      outv += wk * (double)Vbh[(size_t)ik * 64 + lane];
    }
    C[(bb * TT + qa) * 512 + hh * 64 + lane] = (float)outv;
  }
}

// ---------------------------------------------------------------------------
extern "C" void kernel_launch(void* const* d_in, const int* in_sizes, int n_in,
                              void* d_out, int out_size, void* d_ws, size_t ws_size,
                              hipStream_t stream) {
  (void)in_sizes; (void)n_in; (void)out_size;
  const float* x   = (const float*)d_in[0];
  const float* Wq  = (const float*)d_in[1];
  const float* bq  = (const float*)d_in[2];
  const float* Wk  = (const float*)d_in[3];
  const float* bk  = (const float*)d_in[4];
  const float* Wv  = (const float*)d_in[5];
  const float* bv  = (const float*)d_in[6];
  const float* Wo  = (const float*)d_in[7];
  const float* bo  = (const float*)d_in[8];
  const float* Wpi = (const float*)d_in[9];
  const float* bpi = (const float*)d_in[10];
  const float* Wpo = (const float*)d_in[11];
  const float* bpo = (const float*)d_in[12];
  const float* Wta = (const float*)d_in[13];
  const float* bta = (const float*)d_in[14];
  const float* Wtb = (const float*)d_in[15];
  const float* btb = (const float*)d_in[16];
  const float* Wti = (const float*)d_in[17];
  const float* bti = (const float*)d_in[18];
  const float* Wto = (const float*)d_in[19];
  const float* bto = (const float*)d_in[20];

  double* wsd = (double*)d_ws;
  double4* sqd4 = (double4*)wsd;             // 65536 doubles
  double4* skd4 = (double4*)(wsd + 65536);   // 65536 doubles
  double* wphid = wsd + 131072;              // 128
  double* wtaud = wsd + 131200;              // 128
  double* ccd   = wsd + 131328;              // 2 (pad to 131332)
  float* fs = (float*)(wsd + 131332);
  float* Qf = fs;                  // 1,048,576 floats
  float* Kf = fs + 1048576;
  float* Vf = fs + 2097152;
  float* Cf = fs + 3145728;
  float* Kt = fs + 4194304;        // 1,048,576 floats (K^T per bh)
  float* Sc = fs + 5242880;        // 16,777,216 floats (scores, 64 MB)
  const size_t need = (size_t)131332 * 8 + (size_t)(5242880 + 16777216) * 4;

  hipLaunchKernelGGL(k_collapse64, dim3(17), dim3(256), 0, stream,
                     Wpi, bpi, Wpo, bpo, Wti, bti, Wto, bto, wphid, wtaud, ccd);
  hipLaunchKernelGGL(k_gemm_qkv, dim3(24, 32), dim3(256), 0, stream,
                     x, Wq, bq, Wk, bk, Wv, bv, Qf, Kf, Vf);
  hipLaunchKernelGGL(k_tokscal64, dim3(NTOK / 256), dim3(256), 0, stream,
                     Qf, Kf, wphid, Wta, Wtb, wtaud, sqd4, skd4);
  if (ws_size >= need) {
    hipLaunchKernelGGL(k_trans, dim3(16, 16), dim3(256), 0, stream, Kf, Kt);
    hipLaunchKernelGGL(k_score, dim3(16, 8, 16), dim3(256), 0, stream, Qf, Kt, Sc);
    hipLaunchKernelGGL(k_topk, dim3(NTOK / 4), dim3(256), 0, stream,
                       Sc, Vf, sqd4, skd4, ccd, bta, btb, Cf);
  } else {
    hipLaunchKernelGGL(k_attn, dim3(TT / 8, NBH), dim3(256), 0, stream,
                       Qf, Kf, Vf, sqd4, skd4, ccd, bta, btb, Cf);
  }
  hipLaunchKernelGGL(k_gemm, dim3(8, 32), dim3(256), 0, stream,
                     Cf, Wo, bo, (float*)d_out, 0);
}

// Round 8
// 272.800 us; speedup vs baseline: 2.2461x; 1.0117x over previous
//
#include <hip/hip_runtime.h>
#include <math.h>

#define BDIM 2
#define TT 1024
#define NH 8
#define HD 64
#define NTOPK 16
#define NBH 16     // BDIM*NH
#define NTOK 16384 // NBH*TT

// ---------------------------------------------------------------------------
// Collapse the linear-linear pair MLPs into 128-dim fp64 vectors.
// ---------------------------------------------------------------------------
__global__ __launch_bounds__(256) void k_collapse64(
    const float* __restrict__ Wpi, const float* __restrict__ bpi,
    const float* __restrict__ Wpo, const float* __restrict__ bpo,
    const float* __restrict__ Wti, const float* __restrict__ bti,
    const float* __restrict__ Wto, const float* __restrict__ bto,
    double* __restrict__ wphid, double* __restrict__ wtaud,
    double* __restrict__ ccd) {
  int tid = threadIdx.x;
  int blk = blockIdx.x;
  if (blk < 16) {
    int r = blk * 16 + (tid >> 4);
    int l = tid & 15;
    double s = 0.;
    if (r < 128) {
      for (int i = 0; i < 32; ++i)
        s += (double)Wpi[r * 512 + l + 16 * i] * (double)Wpo[l + 16 * i];
    } else {
      int rr = r - 128;
      for (int i = 0; i < 16; ++i)
        s += (double)Wti[rr * 256 + l + 16 * i] * (double)Wto[l + 16 * i];
    }
#pragma unroll
    for (int off = 8; off >= 1; off >>= 1) s += __shfl_xor(s, off, 64);
    if (l == 0) {
      if (r < 128) wphid[r] = s;
      else wtaud[r - 128] = s;
    }
  } else {
    int lane = tid & 63;
    if (tid < 64) {
      double p = 0.;
      for (int c = lane; c < 512; c += 64) p += (double)bpi[c] * (double)Wpo[c];
#pragma unroll
      for (int off = 32; off >= 1; off >>= 1) p += __shfl_xor(p, off, 64);
      if (lane == 0) ccd[0] = p + (double)bpo[0];
    } else if (tid < 128) {
      double p = 0.;
      for (int c = lane; c < 256; c += 64) p += (double)bti[c] * (double)Wto[c];
#pragma unroll
      for (int off = 32; off >= 1; off >>= 1) p += __shfl_xor(p, off, 64);
      if (lane == 0) ccd[1] = p + (double)bto[0];
    }
  }
}

// ---------------------------------------------------------------------------
// fp32 GEMM, strict sequential-k fp32 FMA per output element (BLAS-order —
// this rounding pattern makes top-k selection match the reference).
// BK=32 (half the barriers of BK=16); k order still 0..511 ascending with
// one fmaf per k per element -> bit-exact vs prior rounds.
// ---------------------------------------------------------------------------
__device__ __forceinline__ void gemm_body(
    const float* __restrict__ A, const float* __restrict__ W,
    const float* __restrict__ bias, float* __restrict__ out,
    int bm, int bn, int mode) {
  __shared__ float As[32][68];
  __shared__ float Bs[32][64];
  const int tid = threadIdx.x;
  const int tx = tid & 15;
  const int ty = tid >> 4;
  float acc[4][4] = {{0.f, 0.f, 0.f, 0.f}};
  for (int k0 = 0; k0 < 512; k0 += 32) {
#pragma unroll
    for (int i = 0; i < 2; ++i) {
      int idx = i * 256 + tid;     // 0..511
      int row = idx >> 3;          // 0..63
      int c4 = (idx & 7) << 2;     // 0..28
      float4 av = *(const float4*)&A[(bm + row) * 512 + k0 + c4];
      As[c4 + 0][row] = av.x;
      As[c4 + 1][row] = av.y;
      As[c4 + 2][row] = av.z;
      As[c4 + 3][row] = av.w;
    }
#pragma unroll
    for (int i = 0; i < 2; ++i) {
      int idx = i * 256 + tid;     // 0..511
      int br = idx >> 4;           // 0..31
      int bc = (idx & 15) << 2;
      *(float4*)&Bs[br][bc] = *(const float4*)&W[(k0 + br) * 512 + bn + bc];
    }
    __syncthreads();
#pragma unroll
    for (int kk = 0; kk < 32; ++kk) {
      float4 a = *(const float4*)&As[kk][ty * 4];
      float4 b = *(const float4*)&Bs[kk][tx << 2];
      acc[0][0] = fmaf(a.x, b.x, acc[0][0]);
      acc[0][1] = fmaf(a.x, b.y, acc[0][1]);
      acc[0][2] = fmaf(a.x, b.z, acc[0][2]);
      acc[0][3] = fmaf(a.x, b.w, acc[0][3]);
      acc[1][0] = fmaf(a.y, b.x, acc[1][0]);
      acc[1][1] = fmaf(a.y, b.y, acc[1][1]);
      acc[1][2] = fmaf(a.y, b.z, acc[1][2]);
      acc[1][3] = fmaf(a.y, b.w, acc[1][3]);
      acc[2][0] = fmaf(a.z, b.x, acc[2][0]);
      acc[2][1] = fmaf(a.z, b.y, acc[2][1]);
      acc[2][2] = fmaf(a.z, b.z, acc[2][2]);
      acc[2][3] = fmaf(a.z, b.w, acc[2][3]);
      acc[3][0] = fmaf(a.w, b.x, acc[3][0]);
      acc[3][1] = fmaf(a.w, b.y, acc[3][1]);
      acc[3][2] = fmaf(a.w, b.z, acc[3][2]);
      acc[3][3] = fmaf(a.w, b.w, acc[3][3]);
    }
    __syncthreads();
  }
#pragma unroll
  for (int i = 0; i < 4; ++i) {
    int row = bm + ty * 4 + i;
    float4 r;
    r.x = acc[i][0] + bias[bn + tx * 4 + 0];
    r.y = acc[i][1] + bias[bn + tx * 4 + 1];
    r.z = acc[i][2] + bias[bn + tx * 4 + 2];
    r.w = acc[i][3] + bias[bn + tx * 4 + 3];
    if (mode == 0) {
      *(float4*)&out[row * 512 + bn + tx * 4] = r;
    } else {
      int bb = row >> 10;
      int tt2 = row & 1023;
      int head = bn >> 6;
      *(float4*)&out[(((bb * NH + head) * TT + tt2) << 6) + tx * 4] = r;
    }
  }
}

__global__ __launch_bounds__(256) void k_gemm(
    const float* __restrict__ A, const float* __restrict__ W,
    const float* __restrict__ bias, float* __restrict__ out, int mode) {
  gemm_body(A, W, bias, out, blockIdx.y * 64, blockIdx.x * 64, mode);
}

__global__ __launch_bounds__(256) void k_gemm_qkv(
    const float* __restrict__ A,
    const float* __restrict__ Wq, const float* __restrict__ bq,
    const float* __restrict__ Wk, const float* __restrict__ bk,
    const float* __restrict__ Wv, const float* __restrict__ bv,
    float* __restrict__ Qf, float* __restrict__ Kf, float* __restrict__ Vf) {
  int which = blockIdx.x >> 3;
  int bn = (blockIdx.x & 7) * 64;
  const float* W = (which == 0) ? Wq : (which == 1) ? Wk : Wv;
  const float* b = (which == 0) ? bq : (which == 1) ? bk : bv;
  float* out = (which == 0) ? Qf : (which == 1) ? Kf : Vf;
  gemm_body(A, W, b, out, blockIdx.y * 64, bn, 1);
}

// ---------------------------------------------------------------------------
// Per-token scalars in fp64.
// ---------------------------------------------------------------------------
__global__ __launch_bounds__(256) void k_tokscal64(
    const float* __restrict__ Qg, const float* __restrict__ Kg,
    const double* __restrict__ wphid, const float* __restrict__ Wta,
    const float* __restrict__ Wtb, const double* __restrict__ wtaud,
    double4* __restrict__ sqd4, double4* __restrict__ skd4) {
  __shared__ double wp[128], wa[128], wb[128], wt[128];
  int tid = threadIdx.x;
  if (tid < 128) {
    wp[tid] = wphid[tid];
    wa[tid] = (double)Wta[tid];
    wb[tid] = (double)Wtb[tid];
    wt[tid] = wtaud[tid];
  }
  __syncthreads();
  int tok = blockIdx.x * 256 + tid;
  const float* qr = Qg + (size_t)tok * 64;
  const float* kr = Kg + (size_t)tok * 64;
  double sp = 0., sa = 0., sb = 0., st = 0.;
  double kp = 0., ka = 0., kb2 = 0., kt = 0.;
#pragma unroll
  for (int d = 0; d < 64; ++d) {
    double q = (double)qr[d];
    double k = (double)kr[d];
    sp += q * wp[d];
    sa += q * wa[d];
    sb += q * wb[d];
    st += q * wt[d];
    kp += k * wp[64 + d];
    ka += k * wa[64 + d];
    kb2 += k * wb[64 + d];
    kt += k * wt[64 + d];
  }
  sqd4[tok] = make_double4(sp, sa, sb, st);
  skd4[tok] = make_double4(kp, ka, kb2, kt);
}

// ---------------------------------------------------------------------------
// Score GEMM v2: Sc[bh][q][k] = sum_d Qf[bh][q][d] * Kf[bh][k][d].
// 128(q) x 128(k) tile, 8x8 register tile, BK=32, K-transpose fused into
// the B staging store (no separate k_trans / Kt buffer).
// d ascending, one fmaf per d per element — bit-identical rounding.
// Grid (8 ktiles, 8 qtiles, 16 bh), 256 threads.
// ---------------------------------------------------------------------------
__global__ __launch_bounds__(256) void k_score(
    const float* __restrict__ Qf, const float* __restrict__ Kf,
    float* __restrict__ Sc) {
  __shared__ float As[32][132];   // [d][q], padded
  __shared__ float Bs[32][132];   // [d][k], padded (transposed K)
  const int bn = blockIdx.x * 128;
  const int bm = blockIdx.y * 128;
  const int bh = blockIdx.z;
  const float* A = Qf + (size_t)bh * (TT * 64);
  const float* K = Kf + (size_t)bh * (TT * 64);
  float* out = Sc + (size_t)bh * (TT * 1024);
  const int tid = threadIdx.x;
  const int tx = tid & 15;        // k-group (8 k)
  const int ty = tid >> 4;        // q-group (8 q)
  float acc[8][8];
#pragma unroll
  for (int i = 0; i < 8; ++i)
#pragma unroll
    for (int j = 0; j < 8; ++j) acc[i][j] = 0.f;
  for (int k0 = 0; k0 < 64; k0 += 32) {
#pragma unroll
    for (int i = 0; i < 4; ++i) {
      int idx = i * 256 + tid;      // 0..1023
      int row = idx >> 3;           // 0..127
      int c4 = (idx & 7) << 2;      // 0..28
      float4 av = *(const float4*)&A[(size_t)(bm + row) * 64 + k0 + c4];
      As[c4 + 0][row] = av.x;
      As[c4 + 1][row] = av.y;
      As[c4 + 2][row] = av.z;
      As[c4 + 3][row] = av.w;
      float4 kv = *(const float4*)&K[(size_t)(bn + row) * 64 + k0 + c4];
      Bs[c4 + 0][row] = kv.x;
      Bs[c4 + 1][row] = kv.y;
      Bs[c4 + 2][row] = kv.z;
      Bs[c4 + 3][row] = kv.w;
    }
    __syncthreads();
#pragma unroll
    for (int kk = 0; kk < 32; ++kk) {
      float4 alo = *(const float4*)&As[kk][ty * 8];
      float4 ahi = *(const float4*)&As[kk][ty * 8 + 4];
      float4 blo = *(const float4*)&Bs[kk][tx * 8];
      float4 bhi = *(const float4*)&Bs[kk][tx * 8 + 4];
      float a[8] = {alo.x, alo.y, alo.z, alo.w, ahi.x, ahi.y, ahi.z, ahi.w};
      float b[8] = {blo.x, blo.y, blo.z, blo.w, bhi.x, bhi.y, bhi.z, bhi.w};
#pragma unroll
      for (int i = 0; i < 8; ++i)
#pragma unroll
        for (int j = 0; j < 8; ++j)
          acc[i][j] = fmaf(a[i], b[j], acc[i][j]);
    }
    __syncthreads();
  }
#pragma unroll
  for (int i = 0; i < 8; ++i) {
    float4 r0 = make_float4(acc[i][0], acc[i][1], acc[i][2], acc[i][3]);
    float4 r1 = make_float4(acc[i][4], acc[i][5], acc[i][6], acc[i][7]);
    size_t base = (size_t)(bm + ty * 8 + i) * 1024 + bn + tx * 8;
    *(float4*)&out[base] = r0;
    *(float4*)&out[base + 4] = r1;
  }
}

// ---------------------------------------------------------------------------
// Top-16 + fp32 logits/softmax/attend. One WAVE per query. Selection is
// bit-exact on the fp32 scores (value desc, global index asc).
// ---------------------------------------------------------------------------
__global__ __launch_bounds__(256) void k_topk(
    const float* __restrict__ Sc, const float* __restrict__ Vg,
    const double4* __restrict__ sqd4, const double4* __restrict__ skd4,
    const double* __restrict__ ccd, const float* __restrict__ btaP,
    const float* __restrict__ btbP, float* __restrict__ C) {
  const int tid = threadIdx.x;
  const int lane = tid & 63;
  const int wv = tid >> 6;
  const int qg = blockIdx.x * 4 + wv;   // 0..16383
  const int bh = qg >> 10;
  const int qa = qg & 1023;
  const int bb = bh >> 3;
  const int hh = bh & 7;
  const float* rowp = Sc + (size_t)qg * 1024;
  const float* Vbh = Vg + (size_t)bh * (TT * 64);

  float v[16];
#pragma unroll
  for (int j4 = 0; j4 < 4; ++j4) {
    float4 t = *(const float4*)&rowp[j4 * 256 + lane * 4];
    v[j4 * 4 + 0] = t.x;
    v[j4 * 4 + 1] = t.y;
    v[j4 * 4 + 2] = t.z;
    v[j4 * 4 + 3] = t.w;
  }
  float gv[4];
  int gj[4];
#pragma unroll
  for (int g = 0; g < 4; ++g) {
    gv[g] = v[4 * g];
    gj[g] = 4 * g;
#pragma unroll
    for (int e = 1; e < 4; ++e) {
      if (v[4 * g + e] > gv[g]) { gv[g] = v[4 * g + e]; gj[g] = 4 * g + e; }
    }
  }
  int myk = 0;  // lane it (<16) holds the it-th largest key index
#pragma unroll 1
  for (int it = 0; it < NTOPK; ++it) {
    float bvv = gv[0];
    int bjj = gj[0];
#pragma unroll
    for (int g = 1; g < 4; ++g) {
      if (gv[g] > bvv) { bvv = gv[g]; bjj = gj[g]; }
    }
    // slot -> global key index
    int bj = ((bjj >> 2) << 8) + (lane << 2) + (bjj & 3);
#pragma unroll
    for (int off = 32; off >= 1; off >>= 1) {
      float ov = __shfl_xor(bvv, off, 64);
      int oj = __shfl_xor(bj, off, 64);
      if (ov > bvv || (ov == bvv && oj < bj)) { bvv = ov; bj = oj; }
    }
    if (lane == it) myk = bj;
    int owner = (bj >> 2) & 63;
    int slot = (((bj >> 8) << 2)) | (bj & 3);
    if (lane == owner) {
#pragma unroll
      for (int jj = 0; jj < 16; ++jj)
        if (jj == slot) v[jj] = -INFINITY;
      int g2 = slot >> 2;
#pragma unroll
      for (int g = 0; g < 4; ++g) {
        if (g == g2) {
          float ngv = v[4 * g];
          int ngj = 4 * g;
#pragma unroll
          for (int e = 1; e < 4; ++e) {
            if (v[4 * g + e] > ngv) { ngv = v[4 * g + e]; ngj = 4 * g + e; }
          }
          gv[g] = ngv;
          gj[g] = ngj;
        }
      }
    }
  }
  // fp32 smooth path (selection already fixed; ~1e-5 error << threshold)
  const double cphi = ccd[0];
  const double ctau = ccd[1];
  const double bta0 = (double)btaP[0];
  const double btb0 = (double)btbP[0];
  double4 sq = sqd4[qg];
  float logit = -INFINITY;
  if (lane < 16) {
    double4 sk = skd4[bh * TT + myk];
    float xs = (float)(sq.x + sk.x + cphi);
    float ta = (float)(sq.y + sk.y + bta0);
    float tb = (float)(sq.z + sk.z + btb0);
    float tl = (float)(sq.w + sk.w + ctau);
    float phi = 1.f / (1.f + __expf(-xs));
    float ti = 1.f / (1.f + __expf(-(ta + tb)));          // T_SCALAR = 1
    float tau = fmaxf(tl, 0.f) + log1pf(__expf(-fabsf(tl))) + 1e-6f;
    logit = phi / tau * (1.f - __expf(-tau * ti));
  }
  float m = logit;
#pragma unroll
  for (int off = 8; off >= 1; off >>= 1) m = fmaxf(m, __shfl_xor(m, off, 64));
  float e = (lane < 16) ? __expf(logit - m) : 0.f;
  float ssum = e;
#pragma unroll
  for (int off = 8; off >= 1; off >>= 1) ssum += __shfl_xor(ssum, off, 64);
  float w = e / ssum;
  float outv = 0.f;
#pragma unroll
  for (int k2 = 0; k2 < NTOPK; ++k2) {
    float wk = __shfl(w, k2, 64);
    int ik = __shfl(myk, k2, 64);
    outv = fmaf(wk, Vbh[(size_t)ik * 64 + lane], outv);
  }
  C[(bb * TT + qa) * 512 + hh * 64 + lane] = outv;
}

// ---------------------------------------------------------------------------
// Fallback fused attention (round-5 path) for small workspaces.
// ---------------------------------------------------------------------------
__global__ __launch_bounds__(256) void k_attn(
    const float* __restrict__ Qg, const float* __restrict__ Kg,
    const float* __restrict__ Vg, const double4* __restrict__ sqd4,
    const double4* __restrict__ skd4, const double* __restrict__ ccd,
    const float* __restrict__ btaP, const float* __restrict__ btbP,
    float* __restrict__ C) {
  __shared__ float qs[8][64];
  __shared__ float sc[8][1024];
  const int bh = blockIdx.y;
  const int q0 = blockIdx.x * 8;
  const int tid = threadIdx.x;
  const int lane = tid & 63;
  const int wv = tid >> 6;
  if (tid < 128) {
    int q = tid >> 4, d4 = (tid & 15) << 2;
    *(float4*)&qs[q][d4] = *(const float4*)&Qg[(size_t)(bh * TT + q0 + q) * 64 + d4];
  }
  __syncthreads();
#pragma unroll 1
  for (int c = 0; c < 4; ++c) {
    const int kb = (c * 4 + wv) * 64;
    const float* krow = &Kg[(size_t)(bh * TT + kb + lane) * 64];
    float4 kr[16];
#pragma unroll
    for (int i = 0; i < 16; ++i) kr[i] = *(const float4*)&krow[i * 4];
#pragma unroll
    for (int q = 0; q < 8; ++q) {
      float s = 0.f;
#pragma unroll
      for (int i = 0; i < 16; ++i) {
        float4 q4 = *(const float4*)&qs[q][i * 4];
        s = fmaf(q4.x, kr[i].x, s);
        s = fmaf(q4.y, kr[i].y, s);
        s = fmaf(q4.z, kr[i].z, s);
        s = fmaf(q4.w, kr[i].w, s);
      }
      sc[q][kb + lane] = s;
    }
  }
  __syncthreads();
  const double cphi = ccd[0];
  const double ctau = ccd[1];
  const double bta0 = (double)btaP[0];
  const double btb0 = (double)btbP[0];
  const int bb = bh >> 3;
  const int hh = bh & 7;
  const float* Vbh = Vg + (size_t)bh * (TT * 64);
#pragma unroll 1
  for (int qq = 0; qq < 2; ++qq) {
    const int ql = wv * 2 + qq;
    const int qa = q0 + ql;
    const float* rowp = &sc[ql][0];
    float v[16];
#pragma unroll
    for (int jj = 0; jj < 16; ++jj) v[jj] = rowp[jj * 64 + lane];
    float gv[4];
    int gj[4];
#pragma unroll
    for (int g = 0; g < 4; ++g) {
      gv[g] = v[4 * g];
      gj[g] = 4 * g;
#pragma unroll
      for (int e = 1; e < 4; ++e) {
        if (v[4 * g + e] > gv[g]) { gv[g] = v[4 * g + e]; gj[g] = 4 * g + e; }
      }
    }
    int myk = 0;
#pragma unroll 1
    for (int it = 0; it < NTOPK; ++it) {
      float bvv = gv[0];
      int bjj = gj[0];
#pragma unroll
      for (int g = 1; g < 4; ++g) {
        if (gv[g] > bvv) { bvv = gv[g]; bjj = gj[g]; }
      }
      int bj = bjj * 64 + lane;
#pragma unroll
      for (int off = 32; off >= 1; off >>= 1) {
        float ov = __shfl_xor(bvv, off, 64);
        int oj = __shfl_xor(bj, off, 64);
        if (ov > bvv || (ov == bvv && oj < bj)) { bvv = ov; bj = oj; }
      }
      if (lane == it) myk = bj;
      int owner = bj & 63;
      int slot = bj >> 6;
      if (lane == owner) {
#pragma unroll
        for (int jj = 0; jj < 16; ++jj)
          if (jj == slot) v[jj] = -INFINITY;
        int g2 = slot >> 2;
#pragma unroll
        for (int g = 0; g < 4; ++g) {
          if (g == g2) {
            float ngv = v[4 * g];
            int ngj = 4 * g;
#pragma unroll
            for (int e = 1; e < 4; ++e) {
              if (v[4 * g + e] > ngv) { ngv = v[4 * g + e]; ngj = 4 * g + e; }
            }
            gv[g] = ngv;
            gj[g] = ngj;
          }
        }
      }
    }
    double4 sq = sqd4[bh * TT + qa];
    double logit = -INFINITY;
    if (lane < 16) {
      double4 sk = skd4[bh * TT + myk];
      double phi = 1.0 / (1.0 + exp(-(sq.x + sk.x + cphi)));
      double ta = sq.y + sk.y + bta0;
      double tb = sq.z + sk.z + btb0;
      double ti = 1.0 / (1.0 + exp(-(ta * 1.0 + tb)));
      double tl = sq.w + sk.w + ctau;
      double tau = fmax(tl, 0.0) + log1p(exp(-fabs(tl))) + 1e-6;
      logit = phi / tau * (1.0 - exp(-tau * ti));
    }
    double m = logit;
#pragma unroll
    for (int off = 8; off >= 1; off >>= 1) {
      double om = __shfl_xor(m, off, 64);
      m = fmax(m, om);
    }
    double e = (lane < 16) ? exp(logit - m) : 0.0;
    double ssum = e;
#pragma unroll
    for (int off = 8; off >= 1; off >>= 1) ssum += __shfl_xor(ssum, off, 64);
    double w = e / ssum;
    double outv = 0.0;
#pragma unroll
    for (int k2 = 0; k2 < NTOPK; ++k2) {
      double wk = __shfl(w, k2, 64);
      int ik = __shfl(myk, k2, 64);
      outv += wk * (double)Vbh[(size_t)ik * 64 + lane];
    }
    C[(bb * TT + qa) * 512 + hh * 64 + lane] = (float)outv;
  }
}

// ---------------------------------------------------------------------------
extern "C" void kernel_launch(void* const* d_in, const int* in_sizes, int n_in,
                              void* d_out, int out_size, void* d_ws, size_t ws_size,
                              hipStream_t stream) {
  (void)in_sizes; (void)n_in; (void)out_size;
  const float* x   = (const float*)d_in[0];
  const float* Wq  = (const float*)d_in[1];
  const float* bq  = (const float*)d_in[2];
  const float* Wk  = (const float*)d_in[3];
  const float* bk  = (const float*)d_in[4];
  const float* Wv  = (const float*)d_in[5];
  const float* bv  = (const float*)d_in[6];
  const float* Wo  = (const float*)d_in[7];
  const float* bo  = (const float*)d_in[8];
  const float* Wpi = (const float*)d_in[9];
  const float* bpi = (const float*)d_in[10];
  const float* Wpo = (const float*)d_in[11];
  const float* bpo = (const float*)d_in[12];
  const float* Wta = (const float*)d_in[13];
  const float* bta = (const float*)d_in[14];
  const float* Wtb = (const float*)d_in[15];
  const float* btb = (const float*)d_in[16];
  const float* Wti = (const float*)d_in[17];
  const float* bti = (const float*)d_in[18];
  const float* Wto = (const float*)d_in[19];
  const float* bto = (const float*)d_in[20];

  double* wsd = (double*)d_ws;
  double4* sqd4 = (double4*)wsd;             // 65536 doubles
  double4* skd4 = (double4*)(wsd + 65536);   // 65536 doubles
  double* wphid = wsd + 131072;              // 128
  double* wtaud = wsd + 131200;              // 128
  double* ccd   = wsd + 131328;              // 2 (pad to 131332)
  float* fs = (float*)(wsd + 131332);
  float* Qf = fs;                  // 1,048,576 floats
  float* Kf = fs + 1048576;
  float* Vf = fs + 2097152;
  float* Cf = fs + 3145728;
  float* Sc = fs + 4194304;        // 16,777,216 floats (scores, 64 MB)
  const size_t need = (size_t)131332 * 8 + (size_t)(4194304 + 16777216) * 4;

  hipLaunchKernelGGL(k_collapse64, dim3(17), dim3(256), 0, stream,
                     Wpi, bpi, Wpo, bpo, Wti, bti, Wto, bto, wphid, wtaud, ccd);
  hipLaunchKernelGGL(k_gemm_qkv, dim3(24, 32), dim3(256), 0, stream,
                     x, Wq, bq, Wk, bk, Wv, bv, Qf, Kf, Vf);
  hipLaunchKernelGGL(k_tokscal64, dim3(NTOK / 256), dim3(256), 0, stream,
                     Qf, Kf, wphid, Wta, Wtb, wtaud, sqd4, skd4);
  if (ws_size >= need) {
    hipLaunchKernelGGL(k_score, dim3(8, 8, 16), dim3(256), 0, stream, Qf, Kf, Sc);
    hipLaunchKernelGGL(k_topk, dim3(NTOK / 4), dim3(256), 0, stream,
                       Sc, Vf, sqd4, skd4, ccd, bta, btb, Cf);
  } else {
    hipLaunchKernelGGL(k_attn, dim3(TT / 8, NBH), dim3(256), 0, stream,
                       Qf, Kf, Vf, sqd4, skd4, ccd, bta, btb, Cf);
  }
  hipLaunchKernelGGL(k_gemm, dim3(8, 32), dim3(256), 0, stream,
                     Cf, Wo, bo, (float*)d_out, 0);
}